// Round 10
// baseline (806.772 us; speedup 1.0000x reference)
//
#include <hip/hip_runtime.h>
#include <math.h>

#define N_NODES 50000
#define DIM 64
#define NE 800000
#define NSCAN_BLOCKS ((N_NODES + 255) / 256)   // 196

static __device__ __forceinline__ float bf2f(unsigned short u) {
    return __uint_as_float(((unsigned int)u) << 16);
}
static __device__ __forceinline__ unsigned short f2bf(float f) {
    unsigned int u = __float_as_uint(f);
    u += 0x7fffu + ((u >> 16) & 1u);           // round-to-nearest-even
    return (unsigned short)(u >> 16);
}

// ---------------------------------------------------------------------------
// ws layout:
//   Qf      : N*DIM floats         (f32: wave-uniform read)
//   KVCb    : N*192 ushorts        (bf16 K|V|C interleaved: 384B/node row)
//   bucket_col : NE ints           (CSR position -> col node)
//   counts  : N ints (doubles as fill cursor)
//   offsets : N+1 ints
//   bsums   : 256 ints
//   S       : 1 float (global softmax denominator, atomic)
// ---------------------------------------------------------------------------

// QKV projections: 32 nodes/block, bf16 weights in LDS (32KB -> 5 blocks/CU),
// 8 nodes/thread. K,V + coord packed into interleaved KVC rows.
__global__ __launch_bounds__(256, 5) void k_qkv(
    const float* __restrict__ x, const float* __restrict__ coord,
    const float* __restrict__ Wq, const float* __restrict__ bq,
    const float* __restrict__ Wk, const float* __restrict__ bk,
    const float* __restrict__ Wv, const float* __restrict__ bv,
    float* __restrict__ Qf, unsigned short* __restrict__ KVCb)
{
    __shared__ ushort4 WT2[3][1024];  // 24 KB
    __shared__ float4  xs4[32][16];   // 8 KB

    const int tid  = threadIdx.x;
    const int base = blockIdx.x * 32;

    for (int t = tid; t < 1024; t += 256) {
        int d = t & 63, j2 = t >> 6;
        float4 a = ((const float4*)Wq)[d * 16 + j2];
        float4 b = ((const float4*)Wk)[d * 16 + j2];
        float4 c = ((const float4*)Wv)[d * 16 + j2];
        WT2[0][t] = make_ushort4(f2bf(a.x), f2bf(a.y), f2bf(a.z), f2bf(a.w));
        WT2[1][t] = make_ushort4(f2bf(b.x), f2bf(b.y), f2bf(b.z), f2bf(b.w));
        WT2[2][t] = make_ushort4(f2bf(c.x), f2bf(c.y), f2bf(c.z), f2bf(c.w));
    }
    // coord -> bf16 into interleaved row (+128 ushort offset)
    for (int t = tid; t < 32 * DIM; t += 256) {
        int gn = base + (t >> 6);
        if (gn < N_NODES)
            KVCb[(size_t)gn * 192 + 128 + (t & 63)] =
                f2bf(coord[(size_t)gn * DIM + (t & 63)]);
    }
    for (int t = tid; t < 512; t += 256) {
        int r = t >> 4, j2 = t & 15;
        if (base + r < N_NODES)
            xs4[r][j2] = ((const float4*)x)[(size_t)(base + r) * 16 + j2];
    }
    __syncthreads();

    const int wv = tid >> 6;
    const int d  = tid & 63;
    const float bqv = bq[d], bkv = bk[d], bvv = bv[d];

    float aq[8], ak[8], av[8];
    #pragma unroll
    for (int r = 0; r < 8; ++r) { aq[r] = bqv; ak[r] = bkv; av[r] = bvv; }

    #pragma unroll 4
    for (int j2 = 0; j2 < 16; ++j2) {
        ushort4 uq = WT2[0][j2 * 64 + d];
        ushort4 uk = WT2[1][j2 * 64 + d];
        ushort4 uv = WT2[2][j2 * 64 + d];
        float wqx = bf2f(uq.x), wqy = bf2f(uq.y), wqz = bf2f(uq.z), wqw = bf2f(uq.w);
        float wkx = bf2f(uk.x), wky = bf2f(uk.y), wkz = bf2f(uk.z), wkw = bf2f(uk.w);
        float wvx = bf2f(uv.x), wvy = bf2f(uv.y), wvz = bf2f(uv.z), wvw = bf2f(uv.w);
        #pragma unroll
        for (int r = 0; r < 8; ++r) {
            float4 xv = xs4[wv * 8 + r][j2];   // wave-uniform broadcast
            aq[r] += xv.x * wqx + xv.y * wqy + xv.z * wqz + xv.w * wqw;
            ak[r] += xv.x * wkx + xv.y * wky + xv.z * wkz + xv.w * wkw;
            av[r] += xv.x * wvx + xv.y * wvy + xv.z * wvz + xv.w * wvw;
        }
    }
    #pragma unroll
    for (int r = 0; r < 8; ++r) {
        int n = base + wv * 8 + r;
        if (n < N_NODES) {
            Qf[(size_t)n * DIM + d] = aq[r];
            KVCb[(size_t)n * 192 + d]      = f2bf(ak[r]);
            KVCb[(size_t)n * 192 + 64 + d] = f2bf(av[r]);
        }
    }
}

// histogram of rows; reset S
__global__ __launch_bounds__(256) void k_hist(
    const int* __restrict__ eidx, int* __restrict__ counts,
    float* __restrict__ S)
{
    int e = blockIdx.x * 256 + threadIdx.x;
    if (e < NE) atomicAdd(counts + eidx[e], 1);
    if (e == 0) *S = 0.0f;
}

__global__ __launch_bounds__(256) void k_scan1(
    const int* __restrict__ counts, int* __restrict__ offsets,
    int* __restrict__ bsums)
{
    __shared__ int tmp[256];
    int i = blockIdx.x * 256 + threadIdx.x;
    int v = (i < N_NODES) ? counts[i] : 0;
    tmp[threadIdx.x] = v;
    __syncthreads();
    #pragma unroll
    for (int off = 1; off < 256; off <<= 1) {
        int t = (threadIdx.x >= off) ? tmp[threadIdx.x - off] : 0;
        __syncthreads();
        tmp[threadIdx.x] += t;
        __syncthreads();
    }
    if (i < N_NODES) offsets[i] = tmp[threadIdx.x] - v;   // exclusive
    if (threadIdx.x == 255) bsums[blockIdx.x] = tmp[255];
}

// merged scan2+scan3: each block computes its own bsums-prefix, applies it,
// and initializes the fill cursor.
__global__ __launch_bounds__(256) void k_scan23(
    int* __restrict__ offsets, int* __restrict__ counts,
    const int* __restrict__ bsums)
{
    __shared__ int red[4];
    const int tid = threadIdx.x;
    const int b   = blockIdx.x;
    // sum of bsums[0..b-1]
    int v = (tid < b && tid < NSCAN_BLOCKS) ? bsums[tid] : 0;
    #pragma unroll
    for (int off = 32; off; off >>= 1) v += __shfl_xor(v, off);
    if ((tid & 63) == 0) red[tid >> 6] = v;
    __syncthreads();
    const int pre = red[0] + red[1] + red[2] + red[3];

    int i = b * 256 + tid;
    if (i < N_NODES) {
        int o = offsets[i] + pre;
        offsets[i] = o;
        counts[i]  = o;     // cursor for fill
    }
    if (i == 0) offsets[N_NODES] = NE;
}

__global__ __launch_bounds__(256) void k_fill(
    const int* __restrict__ eidx, int* __restrict__ cursor,
    int* __restrict__ bucket_col)
{
    int e = blockIdx.x * 256 + threadIdx.x;
    if (e < NE) {
        int pos = atomicAdd(cursor + eidx[e], 1);
        bucket_col[pos] = eidx[NE + e];
    }
}

// Fused edge pass: wave per node, 16-lane quarter per edge, lane = 4 dims,
// 2x unrolled. Interleaved KVC rows (one base address per neighbor).
// Unnormalized acc -> d_out; wave psum -> atomicAdd(S).
__global__ __launch_bounds__(256) void k_edge_fused(
    const int* __restrict__ bucket_col, const int* __restrict__ offsets,
    const float* __restrict__ Qf, const unsigned short* __restrict__ KVC,
    const float* __restrict__ coord,
    const float* __restrict__ Wc, const float* __restrict__ bc,
    float* __restrict__ out_x, float* __restrict__ out_c,
    float* __restrict__ S)
{
    const int lane = threadIdx.x & 63;
    const int n = (blockIdx.x * 256 + threadIdx.x) >> 6;
    if (n >= N_NODES) return;
    const int qt = lane >> 4;          // quarter: which edge of the group of 4
    const int sl = lane & 15;          // dim-quad slot (dims 4sl..4sl+3)

    const float4 q4  = ((const float4*)Qf)[(size_t)n * 16 + sl];
    const float4 cr4 = ((const float4*)coord)[(size_t)n * 16 + sl];
    const float4 wc4 = ((const float4*)Wc)[sl];
    const float4 bc4 = ((const float4*)bc)[sl];
    const ushort4* KVC4 = (const ushort4*)KVC;

    const int s = offsets[n], t = offsets[n + 1];
    float4 accx = {0.f, 0.f, 0.f, 0.f};
    float4 accc = {0.f, 0.f, 0.f, 0.f};
    float psum = 0.0f;

    for (int base = s; base < t; base += 8) {
        int pos0 = base + qt;
        int pos1 = base + 4 + qt;
        bool valid0 = pos0 < t, valid1 = pos1 < t;
        int pc0 = valid0 ? pos0 : (t - 1);
        int pc1 = valid1 ? pos1 : (t - 1);
        const ushort4* p0 = KVC4 + (size_t)bucket_col[pc0] * 48;
        const ushort4* p1 = KVC4 + (size_t)bucket_col[pc1] * 48;
        ushort4 ku0 = p0[sl], vu0 = p0[sl + 16], cu0 = p0[sl + 32];
        ushort4 ku1 = p1[sl], vu1 = p1[sl + 16], cu1 = p1[sl + 32];

        // edge 0
        float d0 = q4.x * bf2f(ku0.x) + q4.y * bf2f(ku0.y)
                 + q4.z * bf2f(ku0.z) + q4.w * bf2f(ku0.w);
        float dx0x = cr4.x - bf2f(cu0.x), dx0y = cr4.y - bf2f(cu0.y);
        float dx0z = cr4.z - bf2f(cu0.z), dx0w = cr4.w - bf2f(cu0.w);
        float e0 = dx0x * dx0x + dx0y * dx0y + dx0z * dx0z + dx0w * dx0w;
        // edge 1
        float d1 = q4.x * bf2f(ku1.x) + q4.y * bf2f(ku1.y)
                 + q4.z * bf2f(ku1.z) + q4.w * bf2f(ku1.w);
        float dx1x = cr4.x - bf2f(cu1.x), dx1y = cr4.y - bf2f(cu1.y);
        float dx1z = cr4.z - bf2f(cu1.z), dx1w = cr4.w - bf2f(cu1.w);
        float e1 = dx1x * dx1x + dx1y * dx1y + dx1z * dx1z + dx1w * dx1w;

        #pragma unroll
        for (int off = 1; off <= 8; off <<= 1) {   // reduce within quarter
            d0 += __shfl_xor(d0, off);
            e0 += __shfl_xor(e0, off);
            d1 += __shfl_xor(d1, off);
            e1 += __shfl_xor(e1, off);
        }
        float p0e = valid0 ? __expf(d0) : 0.0f;
        float p1e = valid1 ? __expf(d1) : 0.0f;
        float dist0 = sqrtf(e0), dist1 = sqrtf(e1);
        psum += p0e + p1e;
        accx.x += p0e * bf2f(vu0.x) + p1e * bf2f(vu1.x);
        accx.y += p0e * bf2f(vu0.y) + p1e * bf2f(vu1.y);
        accx.z += p0e * bf2f(vu0.z) + p1e * bf2f(vu1.z);
        accx.w += p0e * bf2f(vu0.w) + p1e * bf2f(vu1.w);
        accc.x += p0e * (dist0 * wc4.x + bc4.x) * dx0x
                + p1e * (dist1 * wc4.x + bc4.x) * dx1x;
        accc.y += p0e * (dist0 * wc4.y + bc4.y) * dx0y
                + p1e * (dist1 * wc4.y + bc4.y) * dx1y;
        accc.z += p0e * (dist0 * wc4.z + bc4.z) * dx0z
                + p1e * (dist1 * wc4.z + bc4.z) * dx1z;
        accc.w += p0e * (dist0 * wc4.w + bc4.w) * dx0w
                + p1e * (dist1 * wc4.w + bc4.w) * dx1w;
    }

    // cross-quarter combine (once per node)
    #pragma unroll
    for (int off = 16; off <= 32; off <<= 1) {
        accx.x += __shfl_xor(accx.x, off);
        accx.y += __shfl_xor(accx.y, off);
        accx.z += __shfl_xor(accx.z, off);
        accx.w += __shfl_xor(accx.w, off);
        accc.x += __shfl_xor(accc.x, off);
        accc.y += __shfl_xor(accc.y, off);
        accc.z += __shfl_xor(accc.z, off);
        accc.w += __shfl_xor(accc.w, off);
        psum   += __shfl_xor(psum, off);
    }
    if (lane < 16) {
        ((float4*)out_x)[(size_t)n * 16 + sl] = accx;   // unnormalized
        ((float4*)out_c)[(size_t)n * 16 + sl] = accc;
    }
    if (lane == 0) atomicAdd(S, psum);
}

// out = residual + out * (1/S), vectorized float4
__global__ __launch_bounds__(256) void k_finalize(
    const float* __restrict__ x, const float* __restrict__ coord,
    const float* __restrict__ S, float* __restrict__ out)
{
    const float inv = 1.0f / *S;
    const int nd4 = (N_NODES * DIM) / 4;      // 800000
    const float4* x4 = (const float4*)x;
    const float4* c4 = (const float4*)coord;
    float4* o4 = (float4*)out;
    for (int i = blockIdx.x * 256 + threadIdx.x; i < 2 * nd4;
         i += gridDim.x * 256) {
        float4 r = (i < nd4) ? x4[i] : c4[i - nd4];
        float4 a = o4[i];
        a.x = r.x + a.x * inv;
        a.y = r.y + a.y * inv;
        a.z = r.z + a.z * inv;
        a.w = r.w + a.w * inv;
        o4[i] = a;
    }
}

extern "C" void kernel_launch(void* const* d_in, const int* in_sizes, int n_in,
                              void* d_out, int out_size, void* d_ws, size_t ws_size,
                              hipStream_t stream)
{
    const float* x     = (const float*)d_in[0];
    const float* coord = (const float*)d_in[1];
    const float* Wq    = (const float*)d_in[2];
    const float* bq    = (const float*)d_in[3];
    const float* Wk    = (const float*)d_in[4];
    const float* bk    = (const float*)d_in[5];
    const float* Wv    = (const float*)d_in[6];
    const float* bv    = (const float*)d_in[7];
    const float* Wc    = (const float*)d_in[8];
    const float* bc    = (const float*)d_in[9];
    const int*   eidx  = (const int*)d_in[10];

    float* out = (float*)d_out;
    float* ws  = (float*)d_ws;

    float* Qf = ws;
    unsigned short* KVCb = (unsigned short*)(Qf + (size_t)N_NODES * DIM);
    int* bucket_col = (int*)(KVCb + (size_t)N_NODES * 192);
    int* counts  = bucket_col + NE;
    int* offsets = counts + N_NODES;
    int* bsums   = offsets + N_NODES + 1;
    float* S     = (float*)(bsums + 256);

    float* out_x = out;
    float* out_c = out + (size_t)N_NODES * DIM;

    // CSR build (row-bucketed column list)
    hipMemsetAsync(counts, 0, (size_t)N_NODES * sizeof(int), stream);
    k_hist  <<<(NE + 255) / 256, 256, 0, stream>>>(eidx, counts, S);
    k_scan1 <<<NSCAN_BLOCKS, 256, 0, stream>>>(counts, offsets, bsums);
    k_scan23<<<NSCAN_BLOCKS, 256, 0, stream>>>(offsets, counts, bsums);
    k_fill  <<<(NE + 255) / 256, 256, 0, stream>>>(eidx, counts, bucket_col);

    // node projections + bf16 packing (32 nodes/block, 5 blocks/CU)
    k_qkv<<<(N_NODES + 31) / 32, 256, 0, stream>>>(
        x, coord, Wq, bq, Wk, bk, Wv, bv, Qf, KVCb);

    // fused edge pass (quarter-per-edge, 2x unrolled), acc -> d_out, Σp -> S
    k_edge_fused<<<(N_NODES * 64 + 255) / 256, 256, 0, stream>>>(
        bucket_col, offsets, Qf, KVCb, coord, Wc, bc, out_x, out_c, S);

    // normalize + residual
    k_finalize<<<2048, 256, 0, stream>>>(x, coord, S, out);
}

// Round 11
// 229.964 us; speedup vs baseline: 3.5082x; 3.5082x over previous
//
#include <hip/hip_runtime.h>
#include <math.h>

#define N_NODES 50000
#define DIM 64
#define NE 800000
#define NSCAN_BLOCKS ((N_NODES + 255) / 256)   // 196

static __device__ __forceinline__ float bf2f(unsigned short u) {
    return __uint_as_float(((unsigned int)u) << 16);
}
static __device__ __forceinline__ unsigned short f2bf(float f) {
    unsigned int u = __float_as_uint(f);
    u += 0x7fffu + ((u >> 16) & 1u);           // round-to-nearest-even
    return (unsigned short)(u >> 16);
}

// ---------------------------------------------------------------------------
// ws layout:
//   Qf      : N*DIM floats         (f32: wave-uniform read)
//   KVCb    : N*192 ushorts        (bf16 K|V|C interleaved: 384B/node row)
//   bucket_col : NE ints           (CSR position -> col node)
//   counts  : N ints (doubles as fill cursor)
//   offsets : N+1 ints
//   bsums   : 256 ints
//   wsum    : N floats             (per-node Σp — independent addresses;
//                                   single-address atomicAdd was 580us of
//                                   serialization at 50k waves [R10])
//   S       : 1 float
// ---------------------------------------------------------------------------

// QKV projections: 32 nodes/block, bf16 weights in LDS (32KB -> 5 blocks/CU),
// 8 nodes/thread. K,V + coord packed into interleaved KVC rows.
__global__ __launch_bounds__(256, 5) void k_qkv(
    const float* __restrict__ x, const float* __restrict__ coord,
    const float* __restrict__ Wq, const float* __restrict__ bq,
    const float* __restrict__ Wk, const float* __restrict__ bk,
    const float* __restrict__ Wv, const float* __restrict__ bv,
    float* __restrict__ Qf, unsigned short* __restrict__ KVCb)
{
    __shared__ ushort4 WT2[3][1024];  // 24 KB
    __shared__ float4  xs4[32][16];   // 8 KB

    const int tid  = threadIdx.x;
    const int base = blockIdx.x * 32;

    for (int t = tid; t < 1024; t += 256) {
        int d = t & 63, j2 = t >> 6;
        float4 a = ((const float4*)Wq)[d * 16 + j2];
        float4 b = ((const float4*)Wk)[d * 16 + j2];
        float4 c = ((const float4*)Wv)[d * 16 + j2];
        WT2[0][t] = make_ushort4(f2bf(a.x), f2bf(a.y), f2bf(a.z), f2bf(a.w));
        WT2[1][t] = make_ushort4(f2bf(b.x), f2bf(b.y), f2bf(b.z), f2bf(b.w));
        WT2[2][t] = make_ushort4(f2bf(c.x), f2bf(c.y), f2bf(c.z), f2bf(c.w));
    }
    // coord -> bf16 into interleaved row (+128 ushort offset)
    for (int t = tid; t < 32 * DIM; t += 256) {
        int gn = base + (t >> 6);
        if (gn < N_NODES)
            KVCb[(size_t)gn * 192 + 128 + (t & 63)] =
                f2bf(coord[(size_t)gn * DIM + (t & 63)]);
    }
    for (int t = tid; t < 512; t += 256) {
        int r = t >> 4, j2 = t & 15;
        if (base + r < N_NODES)
            xs4[r][j2] = ((const float4*)x)[(size_t)(base + r) * 16 + j2];
    }
    __syncthreads();

    const int wv = tid >> 6;
    const int d  = tid & 63;
    const float bqv = bq[d], bkv = bk[d], bvv = bv[d];

    float aq[8], ak[8], av[8];
    #pragma unroll
    for (int r = 0; r < 8; ++r) { aq[r] = bqv; ak[r] = bkv; av[r] = bvv; }

    #pragma unroll 4
    for (int j2 = 0; j2 < 16; ++j2) {
        ushort4 uq = WT2[0][j2 * 64 + d];
        ushort4 uk = WT2[1][j2 * 64 + d];
        ushort4 uv = WT2[2][j2 * 64 + d];
        float wqx = bf2f(uq.x), wqy = bf2f(uq.y), wqz = bf2f(uq.z), wqw = bf2f(uq.w);
        float wkx = bf2f(uk.x), wky = bf2f(uk.y), wkz = bf2f(uk.z), wkw = bf2f(uk.w);
        float wvx = bf2f(uv.x), wvy = bf2f(uv.y), wvz = bf2f(uv.z), wvw = bf2f(uv.w);
        #pragma unroll
        for (int r = 0; r < 8; ++r) {
            float4 xv = xs4[wv * 8 + r][j2];   // wave-uniform broadcast
            aq[r] += xv.x * wqx + xv.y * wqy + xv.z * wqz + xv.w * wqw;
            ak[r] += xv.x * wkx + xv.y * wky + xv.z * wkz + xv.w * wkw;
            av[r] += xv.x * wvx + xv.y * wvy + xv.z * wvz + xv.w * wvw;
        }
    }
    #pragma unroll
    for (int r = 0; r < 8; ++r) {
        int n = base + wv * 8 + r;
        if (n < N_NODES) {
            Qf[(size_t)n * DIM + d] = aq[r];
            KVCb[(size_t)n * 192 + d]      = f2bf(ak[r]);
            KVCb[(size_t)n * 192 + 64 + d] = f2bf(av[r]);
        }
    }
}

__global__ __launch_bounds__(256) void k_hist(
    const int* __restrict__ eidx, int* __restrict__ counts)
{
    int e = blockIdx.x * 256 + threadIdx.x;
    if (e < NE) atomicAdd(counts + eidx[e], 1);
}

__global__ __launch_bounds__(256) void k_scan1(
    const int* __restrict__ counts, int* __restrict__ offsets,
    int* __restrict__ bsums)
{
    __shared__ int tmp[256];
    int i = blockIdx.x * 256 + threadIdx.x;
    int v = (i < N_NODES) ? counts[i] : 0;
    tmp[threadIdx.x] = v;
    __syncthreads();
    #pragma unroll
    for (int off = 1; off < 256; off <<= 1) {
        int t = (threadIdx.x >= off) ? tmp[threadIdx.x - off] : 0;
        __syncthreads();
        tmp[threadIdx.x] += t;
        __syncthreads();
    }
    if (i < N_NODES) offsets[i] = tmp[threadIdx.x] - v;   // exclusive
    if (threadIdx.x == 255) bsums[blockIdx.x] = tmp[255];
}

// merged scan2+scan3: each block computes its own bsums-prefix, applies it,
// and initializes the fill cursor.
__global__ __launch_bounds__(256) void k_scan23(
    int* __restrict__ offsets, int* __restrict__ counts,
    const int* __restrict__ bsums)
{
    __shared__ int red[4];
    const int tid = threadIdx.x;
    const int b   = blockIdx.x;
    int v = (tid < b && tid < NSCAN_BLOCKS) ? bsums[tid] : 0;
    #pragma unroll
    for (int off = 32; off; off >>= 1) v += __shfl_xor(v, off);
    if ((tid & 63) == 0) red[tid >> 6] = v;
    __syncthreads();
    const int pre = red[0] + red[1] + red[2] + red[3];

    int i = b * 256 + tid;
    if (i < N_NODES) {
        int o = offsets[i] + pre;
        offsets[i] = o;
        counts[i]  = o;     // cursor for fill
    }
    if (i == 0) offsets[N_NODES] = NE;
}

__global__ __launch_bounds__(256) void k_fill(
    const int* __restrict__ eidx, int* __restrict__ cursor,
    int* __restrict__ bucket_col)
{
    int e = blockIdx.x * 256 + threadIdx.x;
    if (e < NE) {
        int pos = atomicAdd(cursor + eidx[e], 1);
        bucket_col[pos] = eidx[NE + e];
    }
}

// Fused edge pass: wave per node, 16-lane quarter per edge, lane = 4 dims,
// 2x unrolled. Interleaved KVC rows (one base address per neighbor).
// Unnormalized acc -> d_out; per-node Σp -> wsum[n] (NO shared atomic).
__global__ __launch_bounds__(256) void k_edge_fused(
    const int* __restrict__ bucket_col, const int* __restrict__ offsets,
    const float* __restrict__ Qf, const unsigned short* __restrict__ KVC,
    const float* __restrict__ coord,
    const float* __restrict__ Wc, const float* __restrict__ bc,
    float* __restrict__ out_x, float* __restrict__ out_c,
    float* __restrict__ wsum)
{
    const int lane = threadIdx.x & 63;
    const int n = (blockIdx.x * 256 + threadIdx.x) >> 6;
    if (n >= N_NODES) return;
    const int qt = lane >> 4;          // quarter: which edge of the group of 4
    const int sl = lane & 15;          // dim-quad slot (dims 4sl..4sl+3)

    const float4 q4  = ((const float4*)Qf)[(size_t)n * 16 + sl];
    const float4 cr4 = ((const float4*)coord)[(size_t)n * 16 + sl];
    const float4 wc4 = ((const float4*)Wc)[sl];
    const float4 bc4 = ((const float4*)bc)[sl];
    const ushort4* KVC4 = (const ushort4*)KVC;

    const int s = offsets[n], t = offsets[n + 1];
    float4 accx = {0.f, 0.f, 0.f, 0.f};
    float4 accc = {0.f, 0.f, 0.f, 0.f};
    float psum = 0.0f;

    for (int base = s; base < t; base += 8) {
        int pos0 = base + qt;
        int pos1 = base + 4 + qt;
        bool valid0 = pos0 < t, valid1 = pos1 < t;
        int pc0 = valid0 ? pos0 : (t - 1);
        int pc1 = valid1 ? pos1 : (t - 1);
        const ushort4* p0 = KVC4 + (size_t)bucket_col[pc0] * 48;
        const ushort4* p1 = KVC4 + (size_t)bucket_col[pc1] * 48;
        ushort4 ku0 = p0[sl], vu0 = p0[sl + 16], cu0 = p0[sl + 32];
        ushort4 ku1 = p1[sl], vu1 = p1[sl + 16], cu1 = p1[sl + 32];

        // edge 0
        float d0 = q4.x * bf2f(ku0.x) + q4.y * bf2f(ku0.y)
                 + q4.z * bf2f(ku0.z) + q4.w * bf2f(ku0.w);
        float dx0x = cr4.x - bf2f(cu0.x), dx0y = cr4.y - bf2f(cu0.y);
        float dx0z = cr4.z - bf2f(cu0.z), dx0w = cr4.w - bf2f(cu0.w);
        float e0 = dx0x * dx0x + dx0y * dx0y + dx0z * dx0z + dx0w * dx0w;
        // edge 1
        float d1 = q4.x * bf2f(ku1.x) + q4.y * bf2f(ku1.y)
                 + q4.z * bf2f(ku1.z) + q4.w * bf2f(ku1.w);
        float dx1x = cr4.x - bf2f(cu1.x), dx1y = cr4.y - bf2f(cu1.y);
        float dx1z = cr4.z - bf2f(cu1.z), dx1w = cr4.w - bf2f(cu1.w);
        float e1 = dx1x * dx1x + dx1y * dx1y + dx1z * dx1z + dx1w * dx1w;

        #pragma unroll
        for (int off = 1; off <= 8; off <<= 1) {   // reduce within quarter
            d0 += __shfl_xor(d0, off);
            e0 += __shfl_xor(e0, off);
            d1 += __shfl_xor(d1, off);
            e1 += __shfl_xor(e1, off);
        }
        float p0e = valid0 ? __expf(d0) : 0.0f;
        float p1e = valid1 ? __expf(d1) : 0.0f;
        float dist0 = sqrtf(e0), dist1 = sqrtf(e1);
        psum += p0e + p1e;
        accx.x += p0e * bf2f(vu0.x) + p1e * bf2f(vu1.x);
        accx.y += p0e * bf2f(vu0.y) + p1e * bf2f(vu1.y);
        accx.z += p0e * bf2f(vu0.z) + p1e * bf2f(vu1.z);
        accx.w += p0e * bf2f(vu0.w) + p1e * bf2f(vu1.w);
        accc.x += p0e * (dist0 * wc4.x + bc4.x) * dx0x
                + p1e * (dist1 * wc4.x + bc4.x) * dx1x;
        accc.y += p0e * (dist0 * wc4.y + bc4.y) * dx0y
                + p1e * (dist1 * wc4.y + bc4.y) * dx1y;
        accc.z += p0e * (dist0 * wc4.z + bc4.z) * dx0z
                + p1e * (dist1 * wc4.z + bc4.z) * dx1z;
        accc.w += p0e * (dist0 * wc4.w + bc4.w) * dx0w
                + p1e * (dist1 * wc4.w + bc4.w) * dx1w;
    }

    // cross-quarter combine (once per node)
    #pragma unroll
    for (int off = 16; off <= 32; off <<= 1) {
        accx.x += __shfl_xor(accx.x, off);
        accx.y += __shfl_xor(accx.y, off);
        accx.z += __shfl_xor(accx.z, off);
        accx.w += __shfl_xor(accx.w, off);
        accc.x += __shfl_xor(accc.x, off);
        accc.y += __shfl_xor(accc.y, off);
        accc.z += __shfl_xor(accc.z, off);
        accc.w += __shfl_xor(accc.w, off);
        psum   += __shfl_xor(psum, off);
    }
    if (lane < 16) {
        ((float4*)out_x)[(size_t)n * 16 + sl] = accx;   // unnormalized
        ((float4*)out_c)[(size_t)n * 16 + sl] = accc;
    }
    if (lane == 0) wsum[n] = psum;
}

// deterministic fixed-tree reduction of wsum -> S (single block)
__global__ __launch_bounds__(1024) void k_redsum(
    const float* __restrict__ wsum, float* __restrict__ S)
{
    __shared__ float red[16];
    float a = 0.0f;
    for (int i = threadIdx.x; i < N_NODES; i += 1024) a += wsum[i];
    #pragma unroll
    for (int off = 32; off; off >>= 1) a += __shfl_xor(a, off);
    if ((threadIdx.x & 63) == 0) red[threadIdx.x >> 6] = a;
    __syncthreads();
    if (threadIdx.x == 0) {
        float s = 0.0f;
        #pragma unroll
        for (int w = 0; w < 16; ++w) s += red[w];
        *S = s;
    }
}

// out = residual + out * (1/S), vectorized float4
__global__ __launch_bounds__(256) void k_finalize(
    const float* __restrict__ x, const float* __restrict__ coord,
    const float* __restrict__ S, float* __restrict__ out)
{
    const float inv = 1.0f / *S;
    const int nd4 = (N_NODES * DIM) / 4;      // 800000
    const float4* x4 = (const float4*)x;
    const float4* c4 = (const float4*)coord;
    float4* o4 = (float4*)out;
    for (int i = blockIdx.x * 256 + threadIdx.x; i < 2 * nd4;
         i += gridDim.x * 256) {
        float4 r = (i < nd4) ? x4[i] : c4[i - nd4];
        float4 a = o4[i];
        a.x = r.x + a.x * inv;
        a.y = r.y + a.y * inv;
        a.z = r.z + a.z * inv;
        a.w = r.w + a.w * inv;
        o4[i] = a;
    }
}

extern "C" void kernel_launch(void* const* d_in, const int* in_sizes, int n_in,
                              void* d_out, int out_size, void* d_ws, size_t ws_size,
                              hipStream_t stream)
{
    const float* x     = (const float*)d_in[0];
    const float* coord = (const float*)d_in[1];
    const float* Wq    = (const float*)d_in[2];
    const float* bq    = (const float*)d_in[3];
    const float* Wk    = (const float*)d_in[4];
    const float* bk    = (const float*)d_in[5];
    const float* Wv    = (const float*)d_in[6];
    const float* bv    = (const float*)d_in[7];
    const float* Wc    = (const float*)d_in[8];
    const float* bc    = (const float*)d_in[9];
    const int*   eidx  = (const int*)d_in[10];

    float* out = (float*)d_out;
    float* ws  = (float*)d_ws;

    float* Qf = ws;
    unsigned short* KVCb = (unsigned short*)(Qf + (size_t)N_NODES * DIM);
    int* bucket_col = (int*)(KVCb + (size_t)N_NODES * 192);
    int* counts  = bucket_col + NE;
    int* offsets = counts + N_NODES;
    int* bsums   = offsets + N_NODES + 1;
    float* wsum  = (float*)(bsums + 256);
    float* S     = wsum + N_NODES;

    float* out_x = out;
    float* out_c = out + (size_t)N_NODES * DIM;

    // CSR build (row-bucketed column list)
    hipMemsetAsync(counts, 0, (size_t)N_NODES * sizeof(int), stream);
    k_hist  <<<(NE + 255) / 256, 256, 0, stream>>>(eidx, counts);
    k_scan1 <<<NSCAN_BLOCKS, 256, 0, stream>>>(counts, offsets, bsums);
    k_scan23<<<NSCAN_BLOCKS, 256, 0, stream>>>(offsets, counts, bsums);
    k_fill  <<<(NE + 255) / 256, 256, 0, stream>>>(eidx, counts, bucket_col);

    // node projections + bf16 packing (32 nodes/block, 5 blocks/CU)
    k_qkv<<<(N_NODES + 31) / 32, 256, 0, stream>>>(
        x, coord, Wq, bq, Wk, bk, Wv, bv, Qf, KVCb);

    // fused edge pass (quarter-per-edge, 2x unrolled), acc -> d_out
    k_edge_fused<<<(N_NODES * 64 + 255) / 256, 256, 0, stream>>>(
        bucket_col, offsets, Qf, KVCb, coord, Wc, bc, out_x, out_c, wsum);

    // deterministic global sum, then normalize + residual
    k_redsum<<<1, 1024, 0, stream>>>(wsum, S);
    k_finalize<<<2048, 256, 0, stream>>>(x, coord, S, out);
}

// Round 13
// 221.522 us; speedup vs baseline: 3.6419x; 1.0381x over previous
//
#include <hip/hip_runtime.h>
#include <math.h>

#define N_NODES 50000
#define DIM 64
#define NE 800000
#define NSCAN_BLOCKS ((N_NODES + 255) / 256)   // 196
#define NFILL_BLOCKS ((NE + 255) / 256)        // 3125
#define NQKV_BLOCKS ((N_NODES + 31) / 32)      // 1563

static __device__ __forceinline__ float bf2f(unsigned short u) {
    return __uint_as_float(((unsigned int)u) << 16);
}
static __device__ __forceinline__ unsigned short f2bf(float f) {
    unsigned int u = __float_as_uint(f);
    u += 0x7fffu + ((u >> 16) & 1u);           // round-to-nearest-even
    return (unsigned short)(u >> 16);
}

typedef float v2f __attribute__((ext_vector_type(2)));
// decode 2 fp8(e4m3) from dword half (gfx950 HW cvt; HI must be literal)
template <bool HI>
static __device__ __forceinline__ v2f fp8x2(unsigned int u) {
    return __builtin_amdgcn_cvt_pk_f32_fp8((int)u, HI);
}
static __device__ __forceinline__ unsigned char f2fp8(float f) {
    int p = __builtin_amdgcn_cvt_pk_fp8_f32(f, f, 0, false);
    return (unsigned char)(p & 0xff);
}

// ---------------------------------------------------------------------------
// ws layout:
//   Qf   : N*DIM floats   (f32: wave-uniform read)
//   KVC  : N rows x 256B  (K bf16 128B | V fp8 64B | C fp8 64B = 2 lines/row)
//   bucket_col : NE ints
//   counts  : N ints (doubles as fill cursor)
//   offsets : N+1 ints
//   bsums   : 256 ints
//   wsum    : N floats    (per-node Σp — single-address atomicAdd from 50k
//                          waves was a 580us serialization disaster [R10])
//   S       : 1 float
// ---------------------------------------------------------------------------

// Fused fill + qkv: first NFILL_BLOCKS do CSR fill (latency-bound atomics),
// remaining NQKV_BLOCKS do node projections (compute-bound) — overlapped.
__global__ __launch_bounds__(256, 5) void k_qkv_fill(
    const float* __restrict__ x, const float* __restrict__ coord,
    const float* __restrict__ Wq, const float* __restrict__ bq,
    const float* __restrict__ Wk, const float* __restrict__ bk,
    const float* __restrict__ Wv, const float* __restrict__ bv,
    const int* __restrict__ eidx, int* __restrict__ cursor,
    int* __restrict__ bucket_col,
    float* __restrict__ Qf, unsigned short* __restrict__ KVC)
{
    __shared__ ushort4 WT2[3][1024];  // 24 KB bf16 weights
    __shared__ float4  xs4[32][16];   // 8 KB

    if (blockIdx.x < NFILL_BLOCKS) {   // ---- fill part ----
        int e = blockIdx.x * 256 + threadIdx.x;
        if (e < NE) {
            int pos = atomicAdd(cursor + eidx[e], 1);
            bucket_col[pos] = eidx[NE + e];
        }
        return;
    }

    // ---- qkv part ----
    const int tid  = threadIdx.x;
    const int base = (blockIdx.x - NFILL_BLOCKS) * 32;
    unsigned char* KVB = (unsigned char*)KVC;

    for (int t = tid; t < 1024; t += 256) {
        int d = t & 63, j2 = t >> 6;
        float4 a = ((const float4*)Wq)[d * 16 + j2];
        float4 b = ((const float4*)Wk)[d * 16 + j2];
        float4 c = ((const float4*)Wv)[d * 16 + j2];
        WT2[0][t] = make_ushort4(f2bf(a.x), f2bf(a.y), f2bf(a.z), f2bf(a.w));
        WT2[1][t] = make_ushort4(f2bf(b.x), f2bf(b.y), f2bf(b.z), f2bf(b.w));
        WT2[2][t] = make_ushort4(f2bf(c.x), f2bf(c.y), f2bf(c.z), f2bf(c.w));
    }
    // coord -> fp8 into row segment [192..256)
    for (int t = tid; t < 32 * DIM; t += 256) {
        int gn = base + (t >> 6);
        if (gn < N_NODES)
            KVB[(size_t)gn * 256 + 192 + (t & 63)] =
                f2fp8(coord[(size_t)gn * DIM + (t & 63)]);
    }
    for (int t = tid; t < 512; t += 256) {
        int r = t >> 4, j2 = t & 15;
        if (base + r < N_NODES)
            xs4[r][j2] = ((const float4*)x)[(size_t)(base + r) * 16 + j2];
    }
    __syncthreads();

    const int wv = tid >> 6;
    const int d  = tid & 63;
    const float bqv = bq[d], bkv = bk[d], bvv = bv[d];

    float aq[8], ak[8], av[8];
    #pragma unroll
    for (int r = 0; r < 8; ++r) { aq[r] = bqv; ak[r] = bkv; av[r] = bvv; }

    #pragma unroll 4
    for (int j2 = 0; j2 < 16; ++j2) {
        ushort4 uq = WT2[0][j2 * 64 + d];
        ushort4 uk = WT2[1][j2 * 64 + d];
        ushort4 uv = WT2[2][j2 * 64 + d];
        float wqx = bf2f(uq.x), wqy = bf2f(uq.y), wqz = bf2f(uq.z), wqw = bf2f(uq.w);
        float wkx = bf2f(uk.x), wky = bf2f(uk.y), wkz = bf2f(uk.z), wkw = bf2f(uk.w);
        float wvx = bf2f(uv.x), wvy = bf2f(uv.y), wvz = bf2f(uv.z), wvw = bf2f(uv.w);
        #pragma unroll
        for (int r = 0; r < 8; ++r) {
            float4 xv = xs4[wv * 8 + r][j2];   // wave-uniform broadcast
            aq[r] += xv.x * wqx + xv.y * wqy + xv.z * wqz + xv.w * wqw;
            ak[r] += xv.x * wkx + xv.y * wky + xv.z * wkz + xv.w * wkw;
            av[r] += xv.x * wvx + xv.y * wvy + xv.z * wvz + xv.w * wvw;
        }
    }
    #pragma unroll
    for (int r = 0; r < 8; ++r) {
        int n = base + wv * 8 + r;
        if (n < N_NODES) {
            Qf[(size_t)n * DIM + d] = aq[r];
            KVC[(size_t)n * 128 + d]       = f2bf(ak[r]);    // K bf16
            KVB[(size_t)n * 256 + 128 + d] = f2fp8(av[r]);   // V fp8
        }
    }
}

__global__ __launch_bounds__(256) void k_hist(
    const int* __restrict__ eidx, int* __restrict__ counts)
{
    int e = blockIdx.x * 256 + threadIdx.x;
    if (e < NE) atomicAdd(counts + eidx[e], 1);
}

__global__ __launch_bounds__(256) void k_scan1(
    const int* __restrict__ counts, int* __restrict__ offsets,
    int* __restrict__ bsums)
{
    __shared__ int tmp[256];
    int i = blockIdx.x * 256 + threadIdx.x;
    int v = (i < N_NODES) ? counts[i] : 0;
    tmp[threadIdx.x] = v;
    __syncthreads();
    #pragma unroll
    for (int off = 1; off < 256; off <<= 1) {
        int t = (threadIdx.x >= off) ? tmp[threadIdx.x - off] : 0;
        __syncthreads();
        tmp[threadIdx.x] += t;
        __syncthreads();
    }
    if (i < N_NODES) offsets[i] = tmp[threadIdx.x] - v;   // exclusive
    if (threadIdx.x == 255) bsums[blockIdx.x] = tmp[255];
}

// merged scan2+scan3: each block computes its bsums-prefix, applies it,
// and initializes the fill cursor.
__global__ __launch_bounds__(256) void k_scan23(
    int* __restrict__ offsets, int* __restrict__ counts,
    const int* __restrict__ bsums)
{
    __shared__ int red[4];
    const int tid = threadIdx.x;
    const int b   = blockIdx.x;
    int v = (tid < b && tid < NSCAN_BLOCKS) ? bsums[tid] : 0;
    #pragma unroll
    for (int off = 32; off; off >>= 1) v += __shfl_xor(v, off);
    if ((tid & 63) == 0) red[tid >> 6] = v;
    __syncthreads();
    const int pre = red[0] + red[1] + red[2] + red[3];

    int i = b * 256 + tid;
    if (i < N_NODES) {
        int o = offsets[i] + pre;
        offsets[i] = o;
        counts[i]  = o;     // cursor for fill
    }
    if (i == 0) offsets[N_NODES] = NE;
}

// Fused edge pass: wave per node, 16-lane quarter per edge, lane = 4 dims,
// 2x unrolled. 256B KVC rows = exactly 2 cache lines per gathered neighbor.
__global__ __launch_bounds__(256) void k_edge_fused(
    const int* __restrict__ bucket_col, const int* __restrict__ offsets,
    const float* __restrict__ Qf, const unsigned short* __restrict__ KVC,
    const float* __restrict__ coord,
    const float* __restrict__ Wc, const float* __restrict__ bc,
    float* __restrict__ out_x, float* __restrict__ out_c,
    float* __restrict__ wsum)
{
    const int lane = threadIdx.x & 63;
    const int n = (blockIdx.x * 256 + threadIdx.x) >> 6;
    if (n >= N_NODES) return;
    const int qt = lane >> 4;          // quarter: which edge of the group of 4
    const int sl = lane & 15;          // dim-quad slot (dims 4sl..4sl+3)

    const float4 q4  = ((const float4*)Qf)[(size_t)n * 16 + sl];
    const float4 cr4 = ((const float4*)coord)[(size_t)n * 16 + sl];
    const float4 wc4 = ((const float4*)Wc)[sl];
    const float4 bc4 = ((const float4*)bc)[sl];
    const ushort4* K16 = (const ushort4*)KVC;           // K: idx c*32 + sl
    const unsigned int* U32 = (const unsigned int*)KVC; // V: c*64+32+sl  C: +48

    const int s = offsets[n], t = offsets[n + 1];
    float4 accx = {0.f, 0.f, 0.f, 0.f};
    float4 accc = {0.f, 0.f, 0.f, 0.f};
    float psum = 0.0f;

    for (int base = s; base < t; base += 8) {
        int pos0 = base + qt;
        int pos1 = base + 4 + qt;
        bool v0 = pos0 < t, v1 = pos1 < t;
        int c0 = bucket_col[v0 ? pos0 : (t - 1)];
        int c1 = bucket_col[v1 ? pos1 : (t - 1)];
        ushort4      ku0 = K16[(size_t)c0 * 32 + sl];
        unsigned int vu0 = U32[(size_t)c0 * 64 + 32 + sl];
        unsigned int cu0 = U32[(size_t)c0 * 64 + 48 + sl];
        ushort4      ku1 = K16[(size_t)c1 * 32 + sl];
        unsigned int vu1 = U32[(size_t)c1 * 64 + 32 + sl];
        unsigned int cu1 = U32[(size_t)c1 * 64 + 48 + sl];

        v2f c0a = fp8x2<false>(cu0), c0b = fp8x2<true>(cu0);
        v2f c1a = fp8x2<false>(cu1), c1b = fp8x2<true>(cu1);

        // edge 0
        float d0 = q4.x * bf2f(ku0.x) + q4.y * bf2f(ku0.y)
                 + q4.z * bf2f(ku0.z) + q4.w * bf2f(ku0.w);
        float dx0x = cr4.x - c0a.x, dx0y = cr4.y - c0a.y;
        float dx0z = cr4.z - c0b.x, dx0w = cr4.w - c0b.y;
        float e0 = dx0x * dx0x + dx0y * dx0y + dx0z * dx0z + dx0w * dx0w;
        // edge 1
        float d1 = q4.x * bf2f(ku1.x) + q4.y * bf2f(ku1.y)
                 + q4.z * bf2f(ku1.z) + q4.w * bf2f(ku1.w);
        float dx1x = cr4.x - c1a.x, dx1y = cr4.y - c1a.y;
        float dx1z = cr4.z - c1b.x, dx1w = cr4.w - c1b.y;
        float e1 = dx1x * dx1x + dx1y * dx1y + dx1z * dx1z + dx1w * dx1w;

        #pragma unroll
        for (int off = 1; off <= 8; off <<= 1) {   // reduce within quarter
            d0 += __shfl_xor(d0, off);
            e0 += __shfl_xor(e0, off);
            d1 += __shfl_xor(d1, off);
            e1 += __shfl_xor(e1, off);
        }
        float p0e = v0 ? __expf(d0) : 0.0f;
        float p1e = v1 ? __expf(d1) : 0.0f;
        float dist0 = sqrtf(e0), dist1 = sqrtf(e1);
        psum += p0e + p1e;

        v2f v0a = fp8x2<false>(vu0), v0b = fp8x2<true>(vu0);
        v2f v1a = fp8x2<false>(vu1), v1b = fp8x2<true>(vu1);
        accx.x += p0e * v0a.x + p1e * v1a.x;
        accx.y += p0e * v0a.y + p1e * v1a.y;
        accx.z += p0e * v0b.x + p1e * v1b.x;
        accx.w += p0e * v0b.y + p1e * v1b.y;
        accc.x += p0e * (dist0 * wc4.x + bc4.x) * dx0x
                + p1e * (dist1 * wc4.x + bc4.x) * dx1x;
        accc.y += p0e * (dist0 * wc4.y + bc4.y) * dx0y
                + p1e * (dist1 * wc4.y + bc4.y) * dx1y;
        accc.z += p0e * (dist0 * wc4.z + bc4.z) * dx0z
                + p1e * (dist1 * wc4.z + bc4.z) * dx1z;
        accc.w += p0e * (dist0 * wc4.w + bc4.w) * dx0w
                + p1e * (dist1 * wc4.w + bc4.w) * dx1w;
    }

    // cross-quarter combine (once per node)
    #pragma unroll
    for (int off = 16; off <= 32; off <<= 1) {
        accx.x += __shfl_xor(accx.x, off);
        accx.y += __shfl_xor(accx.y, off);
        accx.z += __shfl_xor(accx.z, off);
        accx.w += __shfl_xor(accx.w, off);
        accc.x += __shfl_xor(accc.x, off);
        accc.y += __shfl_xor(accc.y, off);
        accc.z += __shfl_xor(accc.z, off);
        accc.w += __shfl_xor(accc.w, off);
        psum   += __shfl_xor(psum, off);
    }
    if (lane < 16) {
        ((float4*)out_x)[(size_t)n * 16 + sl] = accx;   // unnormalized
        ((float4*)out_c)[(size_t)n * 16 + sl] = accc;
    }
    if (lane == 0) wsum[n] = psum;
}

// deterministic fixed-tree reduction of wsum -> S (single block)
__global__ __launch_bounds__(1024) void k_redsum(
    const float* __restrict__ wsum, float* __restrict__ S)
{
    __shared__ float red[16];
    float a = 0.0f;
    for (int i = threadIdx.x; i < N_NODES; i += 1024) a += wsum[i];
    #pragma unroll
    for (int off = 32; off; off >>= 1) a += __shfl_xor(a, off);
    if ((threadIdx.x & 63) == 0) red[threadIdx.x >> 6] = a;
    __syncthreads();
    if (threadIdx.x == 0) {
        float s = 0.0f;
        #pragma unroll
        for (int w = 0; w < 16; ++w) s += red[w];
        *S = s;
    }
}

// out = residual + out * (1/S), vectorized float4
__global__ __launch_bounds__(256) void k_finalize(
    const float* __restrict__ x, const float* __restrict__ coord,
    const float* __restrict__ S, float* __restrict__ out)
{
    const float inv = 1.0f / *S;
    const int nd4 = (N_NODES * DIM) / 4;      // 800000
    const float4* x4 = (const float4*)x;
    const float4* c4 = (const float4*)coord;
    float4* o4 = (float4*)out;
    for (int i = blockIdx.x * 256 + threadIdx.x; i < 2 * nd4;
         i += gridDim.x * 256) {
        float4 r = (i < nd4) ? x4[i] : c4[i - nd4];
        float4 a = o4[i];
        a.x = r.x + a.x * inv;
        a.y = r.y + a.y * inv;
        a.z = r.z + a.z * inv;
        a.w = r.w + a.w * inv;
        o4[i] = a;
    }
}

extern "C" void kernel_launch(void* const* d_in, const int* in_sizes, int n_in,
                              void* d_out, int out_size, void* d_ws, size_t ws_size,
                              hipStream_t stream)
{
    const float* x     = (const float*)d_in[0];
    const float* coord = (const float*)d_in[1];
    const float* Wq    = (const float*)d_in[2];
    const float* bq    = (const float*)d_in[3];
    const float* Wk    = (const float*)d_in[4];
    const float* bk    = (const float*)d_in[5];
    const float* Wv    = (const float*)d_in[6];
    const float* bv    = (const float*)d_in[7];
    const float* Wc    = (const float*)d_in[8];
    const float* bc    = (const float*)d_in[9];
    const int*   eidx  = (const int*)d_in[10];

    float* out = (float*)d_out;
    float* ws  = (float*)d_ws;

    float* Qf = ws;
    unsigned short* KVC = (unsigned short*)(Qf + (size_t)N_NODES * DIM);
    int* bucket_col = (int*)(KVC + (size_t)N_NODES * 128);   // 256B rows
    int* counts  = bucket_col + NE;
    int* offsets = counts + N_NODES;
    int* bsums   = offsets + N_NODES + 1;
    float* wsum  = (float*)(bsums + 256);
    float* S     = wsum + N_NODES;

    float* out_x = out;
    float* out_c = out + (size_t)N_NODES * DIM;

    // CSR build (row-bucketed column list)
    (void)hipMemsetAsync(counts, 0, (size_t)N_NODES * sizeof(int), stream);
    k_hist  <<<(NE + 255) / 256, 256, 0, stream>>>(eidx, counts);
    k_scan1 <<<NSCAN_BLOCKS, 256, 0, stream>>>(counts, offsets, bsums);
    k_scan23<<<NSCAN_BLOCKS, 256, 0, stream>>>(offsets, counts, bsums);

    // fused CSR fill + node projections (fp8 V/C packing)
    k_qkv_fill<<<NFILL_BLOCKS + NQKV_BLOCKS, 256, 0, stream>>>(
        x, coord, Wq, bq, Wk, bk, Wv, bv, eidx, counts, bucket_col, Qf, KVC);

    // fused edge pass (quarter-per-edge, 2x unrolled), acc -> d_out
    k_edge_fused<<<(N_NODES * 64 + 255) / 256, 256, 0, stream>>>(
        bucket_col, offsets, Qf, KVC, coord, Wc, bc, out_x, out_c, wsum);

    // deterministic global sum, then normalize + residual
    k_redsum<<<1, 1024, 0, stream>>>(wsum, S);
    k_finalize<<<2048, 256, 0, stream>>>(x, coord, S, out);
}

// Round 14
// 218.109 us; speedup vs baseline: 3.6989x; 1.0157x over previous
//
#include <hip/hip_runtime.h>
#include <math.h>

#define N_NODES 50000
#define DIM 64
#define NE 800000
#define NSCAN_BLOCKS ((N_NODES + 255) / 256)   // 196

static __device__ __forceinline__ float bf2f(unsigned short u) {
    return __uint_as_float(((unsigned int)u) << 16);
}
static __device__ __forceinline__ unsigned short f2bf(float f) {
    unsigned int u = __float_as_uint(f);
    u += 0x7fffu + ((u >> 16) & 1u);           // round-to-nearest-even
    return (unsigned short)(u >> 16);
}

typedef float v2f __attribute__((ext_vector_type(2)));
// decode 2 fp8(e4m3) from dword half (gfx950 HW cvt; HI must be literal)
template <bool HI>
static __device__ __forceinline__ v2f fp8x2(unsigned int u) {
    return __builtin_amdgcn_cvt_pk_f32_fp8((int)u, HI);
}
// pack 4 floats -> 4 fp8 bytes in one dword
static __device__ __forceinline__ unsigned int pack4_fp8(float a, float b,
                                                         float c, float d) {
    int p = __builtin_amdgcn_cvt_pk_fp8_f32(a, b, 0, false);
    p = __builtin_amdgcn_cvt_pk_fp8_f32(c, d, p, true);
    return (unsigned int)p;
}

// ---------------------------------------------------------------------------
// ws layout:
//   Qf   : N*DIM floats   (f32: wave-uniform read)
//   KVC  : N rows x 256B  (K bf16 128B | V fp8 64B | C fp8 64B = 2 lines/row)
//   bucket_col : NE ints
//   counts  : N ints (doubles as fill cursor)
//   offsets : N+1 ints
//   bsums   : 256 ints
//   wsum    : N floats    (per-node Σp; single-address atomicAdd from 50k
//                          waves = 580us serialization [R10]. Fusing fill
//                          into qkv = 32KB-LDS occupancy kill [R13].)
//   S       : 1 float
// ---------------------------------------------------------------------------

// QKV projections: 32 nodes/block, bf16 weights in LDS, 8 nodes/thread.
// All global stores dword+ coalesced (byte stores caused 80MB WRITE [R13]).
__global__ __launch_bounds__(256, 5) void k_qkv(
    const float* __restrict__ x, const float* __restrict__ coord,
    const float* __restrict__ Wq, const float* __restrict__ bq,
    const float* __restrict__ Wk, const float* __restrict__ bk,
    const float* __restrict__ Wv, const float* __restrict__ bv,
    float* __restrict__ Qf, unsigned short* __restrict__ KVC)
{
    __shared__ ushort4 WT2[3][1024];  // 24 KB bf16 weights
    __shared__ float4  xs4[32][16];   // 8 KB (reused as V stage after compute)

    const int tid  = threadIdx.x;
    const int base = blockIdx.x * 32;
    unsigned int* U32 = (unsigned int*)KVC;   // row = 64 dwords

    for (int t = tid; t < 1024; t += 256) {
        int d = t & 63, j2 = t >> 6;
        float4 a = ((const float4*)Wq)[d * 16 + j2];
        float4 b = ((const float4*)Wk)[d * 16 + j2];
        float4 c = ((const float4*)Wv)[d * 16 + j2];
        WT2[0][t] = make_ushort4(f2bf(a.x), f2bf(a.y), f2bf(a.z), f2bf(a.w));
        WT2[1][t] = make_ushort4(f2bf(b.x), f2bf(b.y), f2bf(b.z), f2bf(b.w));
        WT2[2][t] = make_ushort4(f2bf(c.x), f2bf(c.y), f2bf(c.z), f2bf(c.w));
    }
    // coord -> fp8, 4 dims/thread packed into one dword store
    for (int t = tid; t < 512; t += 256) {
        int n = base + (t >> 4), j = t & 15;
        if (n < N_NODES) {
            float4 cv = ((const float4*)coord)[(size_t)n * 16 + j];
            U32[(size_t)n * 64 + 48 + j] = pack4_fp8(cv.x, cv.y, cv.z, cv.w);
        }
    }
    for (int t = tid; t < 512; t += 256) {
        int r = t >> 4, j2 = t & 15;
        if (base + r < N_NODES)
            xs4[r][j2] = ((const float4*)x)[(size_t)(base + r) * 16 + j2];
    }
    __syncthreads();

    const int wv = tid >> 6;
    const int d  = tid & 63;
    const float bqv = bq[d], bkv = bk[d], bvv = bv[d];

    float aq[8], ak[8], av[8];
    #pragma unroll
    for (int r = 0; r < 8; ++r) { aq[r] = bqv; ak[r] = bkv; av[r] = bvv; }

    #pragma unroll 4
    for (int j2 = 0; j2 < 16; ++j2) {
        ushort4 uq = WT2[0][j2 * 64 + d];
        ushort4 uk = WT2[1][j2 * 64 + d];
        ushort4 uv = WT2[2][j2 * 64 + d];
        float wqx = bf2f(uq.x), wqy = bf2f(uq.y), wqz = bf2f(uq.z), wqw = bf2f(uq.w);
        float wkx = bf2f(uk.x), wky = bf2f(uk.y), wkz = bf2f(uk.z), wkw = bf2f(uk.w);
        float wvx = bf2f(uv.x), wvy = bf2f(uv.y), wvz = bf2f(uv.z), wvw = bf2f(uv.w);
        #pragma unroll
        for (int r = 0; r < 8; ++r) {
            float4 xv = xs4[wv * 8 + r][j2];   // wave-uniform broadcast
            aq[r] += xv.x * wqx + xv.y * wqy + xv.z * wqz + xv.w * wqw;
            ak[r] += xv.x * wkx + xv.y * wky + xv.z * wkz + xv.w * wkw;
            av[r] += xv.x * wvx + xv.y * wvy + xv.z * wvz + xv.w * wvw;
        }
    }
    // Qf (f32, 256B/wave) and K (bf16, 128B/wave) stores: coalesced
    #pragma unroll
    for (int r = 0; r < 8; ++r) {
        int n = base + wv * 8 + r;
        if (n < N_NODES) {
            Qf[(size_t)n * DIM + d] = aq[r];
            KVC[(size_t)n * 128 + d] = f2bf(ak[r]);   // K bf16
        }
    }
    // V: stage f32 in LDS (xs4 reused), repack 4 dims/thread -> dword stores
    __syncthreads();   // all xs4 reads done
    float* vf = (float*)xs4;
    #pragma unroll
    for (int r = 0; r < 8; ++r)
        vf[(wv * 8 + r) * 64 + d] = av[r];
    __syncthreads();
    for (int t = tid; t < 512; t += 256) {
        int ln = t >> 4, j = t & 15;
        int n = base + ln;
        if (n < N_NODES) {
            float4 vv = ((const float4*)vf)[ln * 16 + j];
            U32[(size_t)n * 64 + 32 + j] = pack4_fp8(vv.x, vv.y, vv.z, vv.w);
        }
    }
}

__global__ __launch_bounds__(256) void k_hist(
    const int* __restrict__ eidx, int* __restrict__ counts)
{
    int e = blockIdx.x * 256 + threadIdx.x;
    if (e < NE) atomicAdd(counts + eidx[e], 1);
}

__global__ __launch_bounds__(256) void k_scan1(
    const int* __restrict__ counts, int* __restrict__ offsets,
    int* __restrict__ bsums)
{
    __shared__ int tmp[256];
    int i = blockIdx.x * 256 + threadIdx.x;
    int v = (i < N_NODES) ? counts[i] : 0;
    tmp[threadIdx.x] = v;
    __syncthreads();
    #pragma unroll
    for (int off = 1; off < 256; off <<= 1) {
        int t = (threadIdx.x >= off) ? tmp[threadIdx.x - off] : 0;
        __syncthreads();
        tmp[threadIdx.x] += t;
        __syncthreads();
    }
    if (i < N_NODES) offsets[i] = tmp[threadIdx.x] - v;   // exclusive
    if (threadIdx.x == 255) bsums[blockIdx.x] = tmp[255];
}

// merged scan2+scan3
__global__ __launch_bounds__(256) void k_scan23(
    int* __restrict__ offsets, int* __restrict__ counts,
    const int* __restrict__ bsums)
{
    __shared__ int red[4];
    const int tid = threadIdx.x;
    const int b   = blockIdx.x;
    int v = (tid < b && tid < NSCAN_BLOCKS) ? bsums[tid] : 0;
    #pragma unroll
    for (int off = 32; off; off >>= 1) v += __shfl_xor(v, off);
    if ((tid & 63) == 0) red[tid >> 6] = v;
    __syncthreads();
    const int pre = red[0] + red[1] + red[2] + red[3];

    int i = b * 256 + tid;
    if (i < N_NODES) {
        int o = offsets[i] + pre;
        offsets[i] = o;
        counts[i]  = o;     // cursor for fill
    }
    if (i == 0) offsets[N_NODES] = NE;
}

// dedicated fill: zero LDS -> full occupancy for latency-bound atomics
__global__ __launch_bounds__(256) void k_fill(
    const int* __restrict__ eidx, int* __restrict__ cursor,
    int* __restrict__ bucket_col)
{
    int e = blockIdx.x * 256 + threadIdx.x;
    if (e < NE) {
        int pos = atomicAdd(cursor + eidx[e], 1);
        bucket_col[pos] = eidx[NE + e];
    }
}

// Fused edge pass: wave per node, 16-lane quarter per edge, lane = 4 dims,
// 2x unrolled. 256B KVC rows = exactly 2 cache lines per gathered neighbor.
__global__ __launch_bounds__(256) void k_edge_fused(
    const int* __restrict__ bucket_col, const int* __restrict__ offsets,
    const float* __restrict__ Qf, const unsigned short* __restrict__ KVC,
    const float* __restrict__ coord,
    const float* __restrict__ Wc, const float* __restrict__ bc,
    float* __restrict__ out_x, float* __restrict__ out_c,
    float* __restrict__ wsum)
{
    const int lane = threadIdx.x & 63;
    const int n = (blockIdx.x * 256 + threadIdx.x) >> 6;
    if (n >= N_NODES) return;
    const int qt = lane >> 4;          // quarter: which edge of the group of 4
    const int sl = lane & 15;          // dim-quad slot (dims 4sl..4sl+3)

    const float4 q4  = ((const float4*)Qf)[(size_t)n * 16 + sl];
    const float4 cr4 = ((const float4*)coord)[(size_t)n * 16 + sl];
    const float4 wc4 = ((const float4*)Wc)[sl];
    const float4 bc4 = ((const float4*)bc)[sl];
    const ushort4* K16 = (const ushort4*)KVC;           // K: idx c*32 + sl
    const unsigned int* U32 = (const unsigned int*)KVC; // V: c*64+32+sl  C: +48

    const int s = offsets[n], t = offsets[n + 1];
    float4 accx = {0.f, 0.f, 0.f, 0.f};
    float4 accc = {0.f, 0.f, 0.f, 0.f};
    float psum = 0.0f;

    for (int base = s; base < t; base += 8) {
        int pos0 = base + qt;
        int pos1 = base + 4 + qt;
        bool v0 = pos0 < t, v1 = pos1 < t;
        int c0 = bucket_col[v0 ? pos0 : (t - 1)];
        int c1 = bucket_col[v1 ? pos1 : (t - 1)];
        ushort4      ku0 = K16[(size_t)c0 * 32 + sl];
        unsigned int vu0 = U32[(size_t)c0 * 64 + 32 + sl];
        unsigned int cu0 = U32[(size_t)c0 * 64 + 48 + sl];
        ushort4      ku1 = K16[(size_t)c1 * 32 + sl];
        unsigned int vu1 = U32[(size_t)c1 * 64 + 32 + sl];
        unsigned int cu1 = U32[(size_t)c1 * 64 + 48 + sl];

        v2f c0a = fp8x2<false>(cu0), c0b = fp8x2<true>(cu0);
        v2f c1a = fp8x2<false>(cu1), c1b = fp8x2<true>(cu1);

        // edge 0
        float d0 = q4.x * bf2f(ku0.x) + q4.y * bf2f(ku0.y)
                 + q4.z * bf2f(ku0.z) + q4.w * bf2f(ku0.w);
        float dx0x = cr4.x - c0a.x, dx0y = cr4.y - c0a.y;
        float dx0z = cr4.z - c0b.x, dx0w = cr4.w - c0b.y;
        float e0 = dx0x * dx0x + dx0y * dx0y + dx0z * dx0z + dx0w * dx0w;
        // edge 1
        float d1 = q4.x * bf2f(ku1.x) + q4.y * bf2f(ku1.y)
                 + q4.z * bf2f(ku1.z) + q4.w * bf2f(ku1.w);
        float dx1x = cr4.x - c1a.x, dx1y = cr4.y - c1a.y;
        float dx1z = cr4.z - c1b.x, dx1w = cr4.w - c1b.y;
        float e1 = dx1x * dx1x + dx1y * dx1y + dx1z * dx1z + dx1w * dx1w;

        #pragma unroll
        for (int off = 1; off <= 8; off <<= 1) {   // reduce within quarter
            d0 += __shfl_xor(d0, off);
            e0 += __shfl_xor(e0, off);
            d1 += __shfl_xor(d1, off);
            e1 += __shfl_xor(e1, off);
        }
        float p0e = v0 ? __expf(d0) : 0.0f;
        float p1e = v1 ? __expf(d1) : 0.0f;
        float dist0 = sqrtf(e0), dist1 = sqrtf(e1);
        psum += p0e + p1e;

        v2f v0a = fp8x2<false>(vu0), v0b = fp8x2<true>(vu0);
        v2f v1a = fp8x2<false>(vu1), v1b = fp8x2<true>(vu1);
        accx.x += p0e * v0a.x + p1e * v1a.x;
        accx.y += p0e * v0a.y + p1e * v1a.y;
        accx.z += p0e * v0b.x + p1e * v1b.x;
        accx.w += p0e * v0b.y + p1e * v1b.y;
        accc.x += p0e * (dist0 * wc4.x + bc4.x) * dx0x
                + p1e * (dist1 * wc4.x + bc4.x) * dx1x;
        accc.y += p0e * (dist0 * wc4.y + bc4.y) * dx0y
                + p1e * (dist1 * wc4.y + bc4.y) * dx1y;
        accc.z += p0e * (dist0 * wc4.z + bc4.z) * dx0z
                + p1e * (dist1 * wc4.z + bc4.z) * dx1z;
        accc.w += p0e * (dist0 * wc4.w + bc4.w) * dx0w
                + p1e * (dist1 * wc4.w + bc4.w) * dx1w;
    }

    // cross-quarter combine (once per node)
    #pragma unroll
    for (int off = 16; off <= 32; off <<= 1) {
        accx.x += __shfl_xor(accx.x, off);
        accx.y += __shfl_xor(accx.y, off);
        accx.z += __shfl_xor(accx.z, off);
        accx.w += __shfl_xor(accx.w, off);
        accc.x += __shfl_xor(accc.x, off);
        accc.y += __shfl_xor(accc.y, off);
        accc.z += __shfl_xor(accc.z, off);
        accc.w += __shfl_xor(accc.w, off);
        psum   += __shfl_xor(psum, off);
    }
    if (lane < 16) {
        ((float4*)out_x)[(size_t)n * 16 + sl] = accx;   // unnormalized
        ((float4*)out_c)[(size_t)n * 16 + sl] = accc;
    }
    if (lane == 0) wsum[n] = psum;
}

// deterministic fixed-tree reduction of wsum -> S (single block)
__global__ __launch_bounds__(1024) void k_redsum(
    const float* __restrict__ wsum, float* __restrict__ S)
{
    __shared__ float red[16];
    float a = 0.0f;
    for (int i = threadIdx.x; i < N_NODES; i += 1024) a += wsum[i];
    #pragma unroll
    for (int off = 32; off; off >>= 1) a += __shfl_xor(a, off);
    if ((threadIdx.x & 63) == 0) red[threadIdx.x >> 6] = a;
    __syncthreads();
    if (threadIdx.x == 0) {
        float s = 0.0f;
        #pragma unroll
        for (int w = 0; w < 16; ++w) s += red[w];
        *S = s;
    }
}

// out = residual + out * (1/S), vectorized float4
__global__ __launch_bounds__(256) void k_finalize(
    const float* __restrict__ x, const float* __restrict__ coord,
    const float* __restrict__ S, float* __restrict__ out)
{
    const float inv = 1.0f / *S;
    const int nd4 = (N_NODES * DIM) / 4;      // 800000
    const float4* x4 = (const float4*)x;
    const float4* c4 = (const float4*)coord;
    float4* o4 = (float4*)out;
    for (int i = blockIdx.x * 256 + threadIdx.x; i < 2 * nd4;
         i += gridDim.x * 256) {
        float4 r = (i < nd4) ? x4[i] : c4[i - nd4];
        float4 a = o4[i];
        a.x = r.x + a.x * inv;
        a.y = r.y + a.y * inv;
        a.z = r.z + a.z * inv;
        a.w = r.w + a.w * inv;
        o4[i] = a;
    }
}

extern "C" void kernel_launch(void* const* d_in, const int* in_sizes, int n_in,
                              void* d_out, int out_size, void* d_ws, size_t ws_size,
                              hipStream_t stream)
{
    const float* x     = (const float*)d_in[0];
    const float* coord = (const float*)d_in[1];
    const float* Wq    = (const float*)d_in[2];
    const float* bq    = (const float*)d_in[3];
    const float* Wk    = (const float*)d_in[4];
    const float* bk    = (const float*)d_in[5];
    const float* Wv    = (const float*)d_in[6];
    const float* bv    = (const float*)d_in[7];
    const float* Wc    = (const float*)d_in[8];
    const float* bc    = (const float*)d_in[9];
    const int*   eidx  = (const int*)d_in[10];

    float* out = (float*)d_out;
    float* ws  = (float*)d_ws;

    float* Qf = ws;
    unsigned short* KVC = (unsigned short*)(Qf + (size_t)N_NODES * DIM);
    int* bucket_col = (int*)(KVC + (size_t)N_NODES * 128);   // 256B rows
    int* counts  = bucket_col + NE;
    int* offsets = counts + N_NODES;
    int* bsums   = offsets + N_NODES + 1;
    float* wsum  = (float*)(bsums + 256);
    float* S     = wsum + N_NODES;

    float* out_x = out;
    float* out_c = out + (size_t)N_NODES * DIM;

    // CSR build (row-bucketed column list)
    (void)hipMemsetAsync(counts, 0, (size_t)N_NODES * sizeof(int), stream);
    k_hist  <<<(NE + 255) / 256, 256, 0, stream>>>(eidx, counts);
    k_scan1 <<<NSCAN_BLOCKS, 256, 0, stream>>>(counts, offsets, bsums);
    k_scan23<<<NSCAN_BLOCKS, 256, 0, stream>>>(offsets, counts, bsums);
    k_fill  <<<(NE + 255) / 256, 256, 0, stream>>>(eidx, counts, bucket_col);

    // node projections + packing (Q f32, K bf16, V/C fp8 dword-packed)
    k_qkv<<<(N_NODES + 31) / 32, 256, 0, stream>>>(
        x, coord, Wq, bq, Wk, bk, Wv, bv, Qf, KVC);

    // fused edge pass (quarter-per-edge, 2x unrolled), acc -> d_out
    k_edge_fused<<<(N_NODES * 64 + 255) / 256, 256, 0, stream>>>(
        bucket_col, offsets, Qf, KVC, coord, Wc, bc, out_x, out_c, wsum);

    // deterministic global sum, then normalize + residual
    k_redsum<<<1, 1024, 0, stream>>>(wsum, S);
    k_finalize<<<2048, 256, 0, stream>>>(x, coord, S, out);
}

// Round 15
// 201.565 us; speedup vs baseline: 4.0025x; 1.0821x over previous
//
#include <hip/hip_runtime.h>
#include <math.h>

#define N_NODES 50000
#define DIM 64
#define NE 800000
#define NSCAN_BLOCKS ((N_NODES + 255) / 256)   // 196
#define NGROUPS 8                               // row-groups ~ XCDs
#define ROWS_PER_GROUP ((N_NODES + NGROUPS - 1) / NGROUPS)   // 6250
#define NFILL_GRID (392 * NGROUPS)              // 3136 blocks

static __device__ __forceinline__ float bf2f(unsigned short u) {
    return __uint_as_float(((unsigned int)u) << 16);
}
static __device__ __forceinline__ unsigned short f2bf(float f) {
    unsigned int u = __float_as_uint(f);
    u += 0x7fffu + ((u >> 16) & 1u);           // round-to-nearest-even
    return (unsigned short)(u >> 16);
}

typedef float v2f __attribute__((ext_vector_type(2)));
// decode 2 fp8(e4m3) from dword half (gfx950 HW cvt; HI must be literal)
template <bool HI>
static __device__ __forceinline__ v2f fp8x2(unsigned int u) {
    return __builtin_amdgcn_cvt_pk_f32_fp8((int)u, HI);
}
// pack 4 floats -> 4 fp8 bytes in one dword
static __device__ __forceinline__ unsigned int pack4_fp8(float a, float b,
                                                         float c, float d) {
    int p = __builtin_amdgcn_cvt_pk_fp8_f32(a, b, 0, false);
    p = __builtin_amdgcn_cvt_pk_fp8_f32(c, d, p, true);
    return (unsigned int)p;
}

// ---------------------------------------------------------------------------
// ws layout:
//   Qf   : N*DIM floats   (f32: wave-uniform read)
//   KVC  : N rows x 256B  (K bf16 128B | V fp8 64B | C fp8 64B = 2 lines/row)
//   bucket_col : NE ints
//   counts  : N ints (doubles as fill cursor)
//   offsets : N+1 ints
//   bsums   : 256 ints
//   wsum    : N floats
//   S       : 1 float
// Lessons: single-address atomicAdd @50k waves = 580us [R10]; LDS-heavy
// kernel fused with scatter = occupancy kill [R13]; byte scatter stores =
// 16x line-granular write amplification [R13/R14].
// ---------------------------------------------------------------------------

// QKV projections: 32 nodes/block, bf16 weights in LDS, 8 nodes/thread.
__global__ __launch_bounds__(256, 5) void k_qkv(
    const float* __restrict__ x, const float* __restrict__ coord,
    const float* __restrict__ Wq, const float* __restrict__ bq,
    const float* __restrict__ Wk, const float* __restrict__ bk,
    const float* __restrict__ Wv, const float* __restrict__ bv,
    float* __restrict__ Qf, unsigned short* __restrict__ KVC)
{
    __shared__ ushort4 WT2[3][1024];  // 24 KB bf16 weights
    __shared__ float4  xs4[32][16];   // 8 KB (reused as V stage after compute)

    const int tid  = threadIdx.x;
    const int base = blockIdx.x * 32;
    unsigned int* U32 = (unsigned int*)KVC;   // row = 64 dwords

    for (int t = tid; t < 1024; t += 256) {
        int d = t & 63, j2 = t >> 6;
        float4 a = ((const float4*)Wq)[d * 16 + j2];
        float4 b = ((const float4*)Wk)[d * 16 + j2];
        float4 c = ((const float4*)Wv)[d * 16 + j2];
        WT2[0][t] = make_ushort4(f2bf(a.x), f2bf(a.y), f2bf(a.z), f2bf(a.w));
        WT2[1][t] = make_ushort4(f2bf(b.x), f2bf(b.y), f2bf(b.z), f2bf(b.w));
        WT2[2][t] = make_ushort4(f2bf(c.x), f2bf(c.y), f2bf(c.z), f2bf(c.w));
    }
    // coord -> fp8, 4 dims/thread packed into one dword store
    for (int t = tid; t < 512; t += 256) {
        int n = base + (t >> 4), j = t & 15;
        if (n < N_NODES) {
            float4 cv = ((const float4*)coord)[(size_t)n * 16 + j];
            U32[(size_t)n * 64 + 48 + j] = pack4_fp8(cv.x, cv.y, cv.z, cv.w);
        }
    }
    for (int t = tid; t < 512; t += 256) {
        int r = t >> 4, j2 = t & 15;
        if (base + r < N_NODES)
            xs4[r][j2] = ((const float4*)x)[(size_t)(base + r) * 16 + j2];
    }
    __syncthreads();

    const int wv = tid >> 6;
    const int d  = tid & 63;
    const float bqv = bq[d], bkv = bk[d], bvv = bv[d];

    float aq[8], ak[8], av[8];
    #pragma unroll
    for (int r = 0; r < 8; ++r) { aq[r] = bqv; ak[r] = bkv; av[r] = bvv; }

    #pragma unroll 4
    for (int j2 = 0; j2 < 16; ++j2) {
        ushort4 uq = WT2[0][j2 * 64 + d];
        ushort4 uk = WT2[1][j2 * 64 + d];
        ushort4 uv = WT2[2][j2 * 64 + d];
        float wqx = bf2f(uq.x), wqy = bf2f(uq.y), wqz = bf2f(uq.z), wqw = bf2f(uq.w);
        float wkx = bf2f(uk.x), wky = bf2f(uk.y), wkz = bf2f(uk.z), wkw = bf2f(uk.w);
        float wvx = bf2f(uv.x), wvy = bf2f(uv.y), wvz = bf2f(uv.z), wvw = bf2f(uv.w);
        #pragma unroll
        for (int r = 0; r < 8; ++r) {
            float4 xv = xs4[wv * 8 + r][j2];   // wave-uniform broadcast
            aq[r] += xv.x * wqx + xv.y * wqy + xv.z * wqz + xv.w * wqw;
            ak[r] += xv.x * wkx + xv.y * wky + xv.z * wkz + xv.w * wkw;
            av[r] += xv.x * wvx + xv.y * wvy + xv.z * wvz + xv.w * wvw;
        }
    }
    #pragma unroll
    for (int r = 0; r < 8; ++r) {
        int n = base + wv * 8 + r;
        if (n < N_NODES) {
            Qf[(size_t)n * DIM + d] = aq[r];
            KVC[(size_t)n * 128 + d] = f2bf(ak[r]);   // K bf16
        }
    }
    // V: stage f32 in LDS (xs4 reused), repack 4 dims/thread -> dword stores
    __syncthreads();   // all xs4 reads done
    float* vf = (float*)xs4;
    #pragma unroll
    for (int r = 0; r < 8; ++r)
        vf[(wv * 8 + r) * 64 + d] = av[r];
    __syncthreads();
    for (int t = tid; t < 512; t += 256) {
        int ln = t >> 4, j = t & 15;
        int n = base + ln;
        if (n < N_NODES) {
            float4 vv = ((const float4*)vf)[ln * 16 + j];
            U32[(size_t)n * 64 + 32 + j] = pack4_fp8(vv.x, vv.y, vv.z, vv.w);
        }
    }
}

// Row-group-partitioned histogram: group g (blockIdx&7 -> XCD round-robin)
// only counts rows in its range -> atomics cluster into a 25KB L2-local
// region per XCD instead of randomly across 200KB from all 8 XCDs.
__global__ __launch_bounds__(256) void k_hist(
    const int* __restrict__ eidx, int* __restrict__ counts)
{
    const int grp = blockIdx.x & (NGROUPS - 1);
    const int blk = blockIdx.x >> 3;
    const int nblk = gridDim.x >> 3;
    const int rlo = grp * ROWS_PER_GROUP;
    const int rhi = rlo + ROWS_PER_GROUP;
    for (int e = blk * 256 + threadIdx.x; e < NE; e += nblk * 256) {
        int r = eidx[e];
        if (r >= rlo && r < rhi) atomicAdd(counts + r, 1);
    }
}

__global__ __launch_bounds__(256) void k_scan1(
    const int* __restrict__ counts, int* __restrict__ offsets,
    int* __restrict__ bsums)
{
    __shared__ int tmp[256];
    int i = blockIdx.x * 256 + threadIdx.x;
    int v = (i < N_NODES) ? counts[i] : 0;
    tmp[threadIdx.x] = v;
    __syncthreads();
    #pragma unroll
    for (int off = 1; off < 256; off <<= 1) {
        int t = (threadIdx.x >= off) ? tmp[threadIdx.x - off] : 0;
        __syncthreads();
        tmp[threadIdx.x] += t;
        __syncthreads();
    }
    if (i < N_NODES) offsets[i] = tmp[threadIdx.x] - v;   // exclusive
    if (threadIdx.x == 255) bsums[blockIdx.x] = tmp[255];
}

// merged scan2+scan3
__global__ __launch_bounds__(256) void k_scan23(
    int* __restrict__ offsets, int* __restrict__ counts,
    const int* __restrict__ bsums)
{
    __shared__ int red[4];
    const int tid = threadIdx.x;
    const int b   = blockIdx.x;
    int v = (tid < b && tid < NSCAN_BLOCKS) ? bsums[tid] : 0;
    #pragma unroll
    for (int off = 32; off; off >>= 1) v += __shfl_xor(v, off);
    if ((tid & 63) == 0) red[tid >> 6] = v;
    __syncthreads();
    const int pre = red[0] + red[1] + red[2] + red[3];

    int i = b * 256 + tid;
    if (i < N_NODES) {
        int o = offsets[i] + pre;
        offsets[i] = o;
        counts[i]  = o;     // cursor for fill
    }
    if (i == 0) offsets[N_NODES] = NE;
}

// Row-group-partitioned fill: group g only commits edges whose row is in
// its range. All writes to that group's contiguous ~1/8 of bucket_col come
// from one XCD -> L2 merges the 16 writes/line -> writeback ~3MB not 53MB.
__global__ __launch_bounds__(256) void k_fill(
    const int* __restrict__ eidx, int* __restrict__ cursor,
    int* __restrict__ bucket_col)
{
    const int grp = blockIdx.x & (NGROUPS - 1);
    const int blk = blockIdx.x >> 3;
    const int nblk = gridDim.x >> 3;
    const int rlo = grp * ROWS_PER_GROUP;
    const int rhi = rlo + ROWS_PER_GROUP;
    const int* __restrict__ cols = eidx + NE;
    for (int e = blk * 256 + threadIdx.x; e < NE; e += nblk * 256) {
        int r = eidx[e];
        if (r >= rlo && r < rhi) {
            int pos = atomicAdd(cursor + r, 1);
            bucket_col[pos] = cols[e];
        }
    }
}

// Fused edge pass: wave per node, 16-lane quarter per edge, lane = 4 dims,
// 2x unrolled. 256B KVC rows = exactly 2 cache lines per gathered neighbor.
__global__ __launch_bounds__(256) void k_edge_fused(
    const int* __restrict__ bucket_col, const int* __restrict__ offsets,
    const float* __restrict__ Qf, const unsigned short* __restrict__ KVC,
    const float* __restrict__ coord,
    const float* __restrict__ Wc, const float* __restrict__ bc,
    float* __restrict__ out_x, float* __restrict__ out_c,
    float* __restrict__ wsum)
{
    const int lane = threadIdx.x & 63;
    const int n = (blockIdx.x * 256 + threadIdx.x) >> 6;
    if (n >= N_NODES) return;
    const int qt = lane >> 4;          // quarter: which edge of the group of 4
    const int sl = lane & 15;          // dim-quad slot (dims 4sl..4sl+3)

    const float4 q4  = ((const float4*)Qf)[(size_t)n * 16 + sl];
    const float4 cr4 = ((const float4*)coord)[(size_t)n * 16 + sl];
    const float4 wc4 = ((const float4*)Wc)[sl];
    const float4 bc4 = ((const float4*)bc)[sl];
    const ushort4* K16 = (const ushort4*)KVC;           // K: idx c*32 + sl
    const unsigned int* U32 = (const unsigned int*)KVC; // V: c*64+32+sl  C: +48

    const int s = offsets[n], t = offsets[n + 1];
    float4 accx = {0.f, 0.f, 0.f, 0.f};
    float4 accc = {0.f, 0.f, 0.f, 0.f};
    float psum = 0.0f;

    for (int base = s; base < t; base += 8) {
        int pos0 = base + qt;
        int pos1 = base + 4 + qt;
        bool v0 = pos0 < t, v1 = pos1 < t;
        int c0 = bucket_col[v0 ? pos0 : (t - 1)];
        int c1 = bucket_col[v1 ? pos1 : (t - 1)];
        ushort4      ku0 = K16[(size_t)c0 * 32 + sl];
        unsigned int vu0 = U32[(size_t)c0 * 64 + 32 + sl];
        unsigned int cu0 = U32[(size_t)c0 * 64 + 48 + sl];
        ushort4      ku1 = K16[(size_t)c1 * 32 + sl];
        unsigned int vu1 = U32[(size_t)c1 * 64 + 32 + sl];
        unsigned int cu1 = U32[(size_t)c1 * 64 + 48 + sl];

        v2f c0a = fp8x2<false>(cu0), c0b = fp8x2<true>(cu0);
        v2f c1a = fp8x2<false>(cu1), c1b = fp8x2<true>(cu1);

        // edge 0
        float d0 = q4.x * bf2f(ku0.x) + q4.y * bf2f(ku0.y)
                 + q4.z * bf2f(ku0.z) + q4.w * bf2f(ku0.w);
        float dx0x = cr4.x - c0a.x, dx0y = cr4.y - c0a.y;
        float dx0z = cr4.z - c0b.x, dx0w = cr4.w - c0b.y;
        float e0 = dx0x * dx0x + dx0y * dx0y + dx0z * dx0z + dx0w * dx0w;
        // edge 1
        float d1 = q4.x * bf2f(ku1.x) + q4.y * bf2f(ku1.y)
                 + q4.z * bf2f(ku1.z) + q4.w * bf2f(ku1.w);
        float dx1x = cr4.x - c1a.x, dx1y = cr4.y - c1a.y;
        float dx1z = cr4.z - c1b.x, dx1w = cr4.w - c1b.y;
        float e1 = dx1x * dx1x + dx1y * dx1y + dx1z * dx1z + dx1w * dx1w;

        #pragma unroll
        for (int off = 1; off <= 8; off <<= 1) {   // reduce within quarter
            d0 += __shfl_xor(d0, off);
            e0 += __shfl_xor(e0, off);
            d1 += __shfl_xor(d1, off);
            e1 += __shfl_xor(e1, off);
        }
        float p0e = v0 ? __expf(d0) : 0.0f;
        float p1e = v1 ? __expf(d1) : 0.0f;
        float dist0 = sqrtf(e0), dist1 = sqrtf(e1);
        psum += p0e + p1e;

        v2f v0a = fp8x2<false>(vu0), v0b = fp8x2<true>(vu0);
        v2f v1a = fp8x2<false>(vu1), v1b = fp8x2<true>(vu1);
        accx.x += p0e * v0a.x + p1e * v1a.x;
        accx.y += p0e * v0a.y + p1e * v1a.y;
        accx.z += p0e * v0b.x + p1e * v1b.x;
        accx.w += p0e * v0b.y + p1e * v1b.y;
        accc.x += p0e * (dist0 * wc4.x + bc4.x) * dx0x
                + p1e * (dist1 * wc4.x + bc4.x) * dx1x;
        accc.y += p0e * (dist0 * wc4.y + bc4.y) * dx0y
                + p1e * (dist1 * wc4.y + bc4.y) * dx1y;
        accc.z += p0e * (dist0 * wc4.z + bc4.z) * dx0z
                + p1e * (dist1 * wc4.z + bc4.z) * dx1z;
        accc.w += p0e * (dist0 * wc4.w + bc4.w) * dx0w
                + p1e * (dist1 * wc4.w + bc4.w) * dx1w;
    }

    // cross-quarter combine (once per node)
    #pragma unroll
    for (int off = 16; off <= 32; off <<= 1) {
        accx.x += __shfl_xor(accx.x, off);
        accx.y += __shfl_xor(accx.y, off);
        accx.z += __shfl_xor(accx.z, off);
        accx.w += __shfl_xor(accx.w, off);
        accc.x += __shfl_xor(accc.x, off);
        accc.y += __shfl_xor(accc.y, off);
        accc.z += __shfl_xor(accc.z, off);
        accc.w += __shfl_xor(accc.w, off);
        psum   += __shfl_xor(psum, off);
    }
    if (lane < 16) {
        ((float4*)out_x)[(size_t)n * 16 + sl] = accx;   // unnormalized
        ((float4*)out_c)[(size_t)n * 16 + sl] = accc;
    }
    if (lane == 0) wsum[n] = psum;
}

// deterministic fixed-tree reduction of wsum -> S (single block)
__global__ __launch_bounds__(1024) void k_redsum(
    const float* __restrict__ wsum, float* __restrict__ S)
{
    __shared__ float red[16];
    float a = 0.0f;
    for (int i = threadIdx.x; i < N_NODES; i += 1024) a += wsum[i];
    #pragma unroll
    for (int off = 32; off; off >>= 1) a += __shfl_xor(a, off);
    if ((threadIdx.x & 63) == 0) red[threadIdx.x >> 6] = a;
    __syncthreads();
    if (threadIdx.x == 0) {
        float s = 0.0f;
        #pragma unroll
        for (int w = 0; w < 16; ++w) s += red[w];
        *S = s;
    }
}

// out = residual + out * (1/S), vectorized float4
__global__ __launch_bounds__(256) void k_finalize(
    const float* __restrict__ x, const float* __restrict__ coord,
    const float* __restrict__ S, float* __restrict__ out)
{
    const float inv = 1.0f / *S;
    const int nd4 = (N_NODES * DIM) / 4;      // 800000
    const float4* x4 = (const float4*)x;
    const float4* c4 = (const float4*)coord;
    float4* o4 = (float4*)out;
    for (int i = blockIdx.x * 256 + threadIdx.x; i < 2 * nd4;
         i += gridDim.x * 256) {
        float4 r = (i < nd4) ? x4[i] : c4[i - nd4];
        float4 a = o4[i];
        a.x = r.x + a.x * inv;
        a.y = r.y + a.y * inv;
        a.z = r.z + a.z * inv;
        a.w = r.w + a.w * inv;
        o4[i] = a;
    }
}

extern "C" void kernel_launch(void* const* d_in, const int* in_sizes, int n_in,
                              void* d_out, int out_size, void* d_ws, size_t ws_size,
                              hipStream_t stream)
{
    const float* x     = (const float*)d_in[0];
    const float* coord = (const float*)d_in[1];
    const float* Wq    = (const float*)d_in[2];
    const float* bq    = (const float*)d_in[3];
    const float* Wk    = (const float*)d_in[4];
    const float* bk    = (const float*)d_in[5];
    const float* Wv    = (const float*)d_in[6];
    const float* bv    = (const float*)d_in[7];
    const float* Wc    = (const float*)d_in[8];
    const float* bc    = (const float*)d_in[9];
    const int*   eidx  = (const int*)d_in[10];

    float* out = (float*)d_out;
    float* ws  = (float*)d_ws;

    float* Qf = ws;
    unsigned short* KVC = (unsigned short*)(Qf + (size_t)N_NODES * DIM);
    int* bucket_col = (int*)(KVC + (size_t)N_NODES * 128);   // 256B rows
    int* counts  = bucket_col + NE;
    int* offsets = counts + N_NODES;
    int* bsums   = offsets + N_NODES + 1;
    float* wsum  = (float*)(bsums + 256);
    float* S     = wsum + N_NODES;

    float* out_x = out;
    float* out_c = out + (size_t)N_NODES * DIM;

    // CSR build (row-bucketed column list), row-group-partitioned scatter
    (void)hipMemsetAsync(counts, 0, (size_t)N_NODES * sizeof(int), stream);
    k_hist  <<<NFILL_GRID, 256, 0, stream>>>(eidx, counts);
    k_scan1 <<<NSCAN_BLOCKS, 256, 0, stream>>>(counts, offsets, bsums);
    k_scan23<<<NSCAN_BLOCKS, 256, 0, stream>>>(offsets, counts, bsums);
    k_fill  <<<NFILL_GRID, 256, 0, stream>>>(eidx, counts, bucket_col);

    // node projections + packing (Q f32, K bf16, V/C fp8 dword-packed)
    k_qkv<<<(N_NODES + 31) / 32, 256, 0, stream>>>(
        x, coord, Wq, bq, Wk, bk, Wv, bv, Qf, KVC);

    // fused edge pass (quarter-per-edge, 2x unrolled), acc -> d_out
    k_edge_fused<<<(N_NODES * 64 + 255) / 256, 256, 0, stream>>>(
        bucket_col, offsets, Qf, KVC, coord, Wc, bc, out_x, out_c, wsum);

    // deterministic global sum, then normalize + residual
    k_redsum<<<1, 1024, 0, stream>>>(wsum, S);
    k_finalize<<<2048, 256, 0, stream>>>(x, coord, S, out);
}

// Round 16
// 198.605 us; speedup vs baseline: 4.0622x; 1.0149x over previous
//
#include <hip/hip_runtime.h>
#include <math.h>

#define N_NODES 50000
#define DIM 64
#define NE 800000
#define NSCAN_BLOCKS ((N_NODES + 255) / 256)   // 196
#define NGROUPS 8                               // row-groups ~ XCDs
#define ROWS_PER_GROUP ((N_NODES + NGROUPS - 1) / NGROUPS)   // 6250
#define NFILL_GRID (392 * NGROUPS)              // 3136 blocks

static __device__ __forceinline__ unsigned short f2bf(float f) {
    unsigned int u = __float_as_uint(f);
    u += 0x7fffu + ((u >> 16) & 1u);
    return (unsigned short)(u >> 16);
}
static __device__ __forceinline__ float bf2f(unsigned short u) {
    return __uint_as_float(((unsigned int)u) << 16);
}

typedef _Float16 half2v __attribute__((ext_vector_type(2)));
typedef float v2f __attribute__((ext_vector_type(2)));

static __device__ __forceinline__ half2v u2h(unsigned int u) {
    union { unsigned int u; half2v h; } x; x.u = u; return x.h;
}
static __device__ __forceinline__ unsigned short f2h(float f) {
    union { _Float16 h; unsigned short s; } x; x.h = (_Float16)f; return x.s;
}

#if defined(__has_builtin)
#  if __has_builtin(__builtin_amdgcn_fdot2)
#    define HAVE_FDOT2 1
#  endif
#endif

// acc += dot(f16x2, f16x2) — v_dot2_f32_f16 when available
static __device__ __forceinline__ float dot2acc(unsigned int qa,
                                                unsigned int ka, float c) {
#ifdef HAVE_FDOT2
    return __builtin_amdgcn_fdot2(u2h(qa), u2h(ka), c, false);
#else
    half2v q = u2h(qa), k = u2h(ka);
    return c + (float)q.x * (float)k.x + (float)q.y * (float)k.y;
#endif
}

// decode 2 fp8(e4m3) from dword half (HI must be literal)
template <bool HI>
static __device__ __forceinline__ v2f fp8x2(unsigned int u) {
    return __builtin_amdgcn_cvt_pk_f32_fp8((int)u, HI);
}
// pack 4 floats -> 4 fp8 bytes in one dword
static __device__ __forceinline__ unsigned int pack4_fp8(float a, float b,
                                                         float c, float d) {
    int p = __builtin_amdgcn_cvt_pk_fp8_f32(a, b, 0, false);
    p = __builtin_amdgcn_cvt_pk_fp8_f32(c, d, p, true);
    return (unsigned int)p;
}

// ---------------------------------------------------------------------------
// ws layout:
//   Qh   : N*64 ushorts   (f16, pre-scaled by log2(e); wave-uniform read)
//   KVC  : N rows x 256B  (K f16 128B | V,C fp8 dword-interleaved 128B)
//   bucket_col : NE ints
//   counts  : N ints (doubles as fill cursor)
//   offsets : N+1 ints
//   bsums   : 256 ints
//   wsum    : N floats
//   S       : 1 float
// Lessons: single-address atomicAdd @50k waves = 580us [R10]; LDS-heavy
// kernel fused with scatter = occupancy kill [R13]; sub-dword scatter
// stores = 16x line write amplification [R13/R14]; row-group partition
// makes scatter L2-local [R15].
// ---------------------------------------------------------------------------

// QKV projections: 32 nodes/block, bf16 weights in LDS, 8 nodes/thread.
__global__ __launch_bounds__(256, 5) void k_qkv(
    const float* __restrict__ x, const float* __restrict__ coord,
    const float* __restrict__ Wq, const float* __restrict__ bq,
    const float* __restrict__ Wk, const float* __restrict__ bk,
    const float* __restrict__ Wv, const float* __restrict__ bv,
    unsigned short* __restrict__ Qh, unsigned short* __restrict__ KVC)
{
    __shared__ ushort4 WT2[3][1024];  // 24 KB bf16 weights
    __shared__ float4  xs4[32][16];   // 8 KB (reused as V stage after compute)

    const int tid  = threadIdx.x;
    const int base = blockIdx.x * 32;

    for (int t = tid; t < 1024; t += 256) {
        int d = t & 63, j2 = t >> 6;
        float4 a = ((const float4*)Wq)[d * 16 + j2];
        float4 b = ((const float4*)Wk)[d * 16 + j2];
        float4 c = ((const float4*)Wv)[d * 16 + j2];
        WT2[0][t] = make_ushort4(f2bf(a.x), f2bf(a.y), f2bf(a.z), f2bf(a.w));
        WT2[1][t] = make_ushort4(f2bf(b.x), f2bf(b.y), f2bf(b.z), f2bf(b.w));
        WT2[2][t] = make_ushort4(f2bf(c.x), f2bf(c.y), f2bf(c.z), f2bf(c.w));
    }
    for (int t = tid; t < 512; t += 256) {
        int r = t >> 4, j2 = t & 15;
        if (base + r < N_NODES)
            xs4[r][j2] = ((const float4*)x)[(size_t)(base + r) * 16 + j2];
    }
    __syncthreads();

    const int wv = tid >> 6;
    const int d  = tid & 63;
    const float bqv = bq[d], bkv = bk[d], bvv = bv[d];

    float aq[8], ak[8], av[8];
    #pragma unroll
    for (int r = 0; r < 8; ++r) { aq[r] = bqv; ak[r] = bkv; av[r] = bvv; }

    #pragma unroll 4
    for (int j2 = 0; j2 < 16; ++j2) {
        ushort4 uq = WT2[0][j2 * 64 + d];
        ushort4 uk = WT2[1][j2 * 64 + d];
        ushort4 uv = WT2[2][j2 * 64 + d];
        float wqx = bf2f(uq.x), wqy = bf2f(uq.y), wqz = bf2f(uq.z), wqw = bf2f(uq.w);
        float wkx = bf2f(uk.x), wky = bf2f(uk.y), wkz = bf2f(uk.z), wkw = bf2f(uk.w);
        float wvx = bf2f(uv.x), wvy = bf2f(uv.y), wvz = bf2f(uv.z), wvw = bf2f(uv.w);
        #pragma unroll
        for (int r = 0; r < 8; ++r) {
            float4 xv = xs4[wv * 8 + r][j2];   // wave-uniform broadcast
            aq[r] += xv.x * wqx + xv.y * wqy + xv.z * wqz + xv.w * wqw;
            ak[r] += xv.x * wkx + xv.y * wky + xv.z * wkz + xv.w * wkw;
            av[r] += xv.x * wvx + xv.y * wvy + xv.z * wvz + xv.w * wvw;
        }
    }
    // Q (f16, pre-scaled by log2e) and K (f16) stores: coalesced 128B/wave
    #pragma unroll
    for (int r = 0; r < 8; ++r) {
        int n = base + wv * 8 + r;
        if (n < N_NODES) {
            Qh[(size_t)n * 64 + d]  = f2h(aq[r] * 1.44269504f);
            KVC[(size_t)n * 128 + d] = f2h(ak[r]);
        }
    }
    // V: stage f32 in LDS, then pack {V,C} fp8 dwords -> one uint2 store
    __syncthreads();   // all xs4 reads done
    float* vf = (float*)xs4;
    #pragma unroll
    for (int r = 0; r < 8; ++r)
        vf[(wv * 8 + r) * 64 + d] = av[r];
    __syncthreads();
    uint2* VC2 = (uint2*)KVC;           // row = 32 uint2 (256B)
    for (int t = tid; t < 512; t += 256) {
        int ln = t >> 4, j = t & 15;
        int n = base + ln;
        if (n < N_NODES) {
            float4 vv = ((const float4*)vf)[ln * 16 + j];
            float4 cv = ((const float4*)coord)[(size_t)n * 16 + j];
            uint2 o;
            o.x = pack4_fp8(vv.x, vv.y, vv.z, vv.w);
            o.y = pack4_fp8(cv.x, cv.y, cv.z, cv.w);
            VC2[(size_t)n * 32 + 16 + j] = o;
        }
    }
}

// Row-group-partitioned histogram (group ~ XCD; atomics L2-local)
__global__ __launch_bounds__(256) void k_hist(
    const int* __restrict__ eidx, int* __restrict__ counts)
{
    const int grp = blockIdx.x & (NGROUPS - 1);
    const int blk = blockIdx.x >> 3;
    const int nblk = gridDim.x >> 3;
    const int rlo = grp * ROWS_PER_GROUP;
    const int rhi = rlo + ROWS_PER_GROUP;
    for (int e = blk * 256 + threadIdx.x; e < NE; e += nblk * 256) {
        int r = eidx[e];
        if (r >= rlo && r < rhi) atomicAdd(counts + r, 1);
    }
}

__global__ __launch_bounds__(256) void k_scan1(
    const int* __restrict__ counts, int* __restrict__ offsets,
    int* __restrict__ bsums)
{
    __shared__ int tmp[256];
    int i = blockIdx.x * 256 + threadIdx.x;
    int v = (i < N_NODES) ? counts[i] : 0;
    tmp[threadIdx.x] = v;
    __syncthreads();
    #pragma unroll
    for (int off = 1; off < 256; off <<= 1) {
        int t = (threadIdx.x >= off) ? tmp[threadIdx.x - off] : 0;
        __syncthreads();
        tmp[threadIdx.x] += t;
        __syncthreads();
    }
    if (i < N_NODES) offsets[i] = tmp[threadIdx.x] - v;   // exclusive
    if (threadIdx.x == 255) bsums[blockIdx.x] = tmp[255];
}

// merged scan2+scan3
__global__ __launch_bounds__(256) void k_scan23(
    int* __restrict__ offsets, int* __restrict__ counts,
    const int* __restrict__ bsums)
{
    __shared__ int red[4];
    const int tid = threadIdx.x;
    const int b   = blockIdx.x;
    int v = (tid < b && tid < NSCAN_BLOCKS) ? bsums[tid] : 0;
    #pragma unroll
    for (int off = 32; off; off >>= 1) v += __shfl_xor(v, off);
    if ((tid & 63) == 0) red[tid >> 6] = v;
    __syncthreads();
    const int pre = red[0] + red[1] + red[2] + red[3];

    int i = b * 256 + tid;
    if (i < N_NODES) {
        int o = offsets[i] + pre;
        offsets[i] = o;
        counts[i]  = o;     // cursor for fill
    }
    if (i == 0) offsets[N_NODES] = NE;
}

// Row-group-partitioned fill (writes L2-local -> no 16x amplification)
__global__ __launch_bounds__(256) void k_fill(
    const int* __restrict__ eidx, int* __restrict__ cursor,
    int* __restrict__ bucket_col)
{
    const int grp = blockIdx.x & (NGROUPS - 1);
    const int blk = blockIdx.x >> 3;
    const int nblk = gridDim.x >> 3;
    const int rlo = grp * ROWS_PER_GROUP;
    const int rhi = rlo + ROWS_PER_GROUP;
    const int* __restrict__ cols = eidx + NE;
    for (int e = blk * 256 + threadIdx.x; e < NE; e += nblk * 256) {
        int r = eidx[e];
        if (r >= rlo && r < rhi) {
            int pos = atomicAdd(cursor + r, 1);
            bucket_col[pos] = cols[e];
        }
    }
}

// Fused edge pass: wave per node, 16-lane quarter per edge, lane = 4 dims,
// 2x unrolled. K f16 (fdot2), V/C fp8 (one uint2 load), 2 lines/neighbor.
__global__ __launch_bounds__(256) void k_edge_fused(
    const int* __restrict__ bucket_col, const int* __restrict__ offsets,
    const unsigned short* __restrict__ Qh, const unsigned short* __restrict__ KVC,
    const float* __restrict__ coord,
    const float* __restrict__ Wc, const float* __restrict__ bc,
    float* __restrict__ out_x, float* __restrict__ out_c,
    float* __restrict__ wsum)
{
    const int lane = threadIdx.x & 63;
    const int n = (blockIdx.x * 256 + threadIdx.x) >> 6;
    if (n >= N_NODES) return;
    const int qt = lane >> 4;          // quarter: which edge of the group of 4
    const int sl = lane & 15;          // dim-quad slot (dims 4sl..4sl+3)

    const uint2 q2   = ((const uint2*)Qh)[(size_t)n * 16 + sl];   // 2x f16x2
    const float4 cr4 = ((const float4*)coord)[(size_t)n * 16 + sl];
    const float4 wc4 = ((const float4*)Wc)[sl];
    const float4 bc4 = ((const float4*)bc)[sl];
    const uint2* K2  = (const uint2*)KVC;    // K: idx c*32 + sl
    const uint2* VC2 = (const uint2*)KVC;    // VC: idx c*32 + 16 + sl

    const int s = offsets[n], t = offsets[n + 1];
    float4 accx = {0.f, 0.f, 0.f, 0.f};
    float4 accc = {0.f, 0.f, 0.f, 0.f};
    float psum = 0.0f;

    for (int base = s; base < t; base += 8) {
        int pos0 = base + qt;
        int pos1 = base + 4 + qt;
        bool v0 = pos0 < t, v1 = pos1 < t;
        int c0 = bucket_col[v0 ? pos0 : (t - 1)];
        int c1 = bucket_col[v1 ? pos1 : (t - 1)];
        uint2 k0  = K2[(size_t)c0 * 32 + sl];
        uint2 vc0 = VC2[(size_t)c0 * 32 + 16 + sl];
        uint2 k1  = K2[(size_t)c1 * 32 + sl];
        uint2 vc1 = VC2[(size_t)c1 * 32 + 16 + sl];

        v2f c0a = fp8x2<false>(vc0.y), c0b = fp8x2<true>(vc0.y);
        v2f c1a = fp8x2<false>(vc1.y), c1b = fp8x2<true>(vc1.y);

        // logits via f16 dot2 (Q pre-scaled by log2e -> exp2 later)
        float d0 = dot2acc(q2.y, k0.y, dot2acc(q2.x, k0.x, 0.0f));
        float d1 = dot2acc(q2.y, k1.y, dot2acc(q2.x, k1.x, 0.0f));

        float dx0x = cr4.x - c0a.x, dx0y = cr4.y - c0a.y;
        float dx0z = cr4.z - c0b.x, dx0w = cr4.w - c0b.y;
        float e0 = dx0x * dx0x + dx0y * dx0y + dx0z * dx0z + dx0w * dx0w;
        float dx1x = cr4.x - c1a.x, dx1y = cr4.y - c1a.y;
        float dx1z = cr4.z - c1b.x, dx1w = cr4.w - c1b.y;
        float e1 = dx1x * dx1x + dx1y * dx1y + dx1z * dx1z + dx1w * dx1w;

        #pragma unroll
        for (int off = 1; off <= 8; off <<= 1) {   // reduce within quarter
            d0 += __shfl_xor(d0, off);
            e0 += __shfl_xor(e0, off);
            d1 += __shfl_xor(d1, off);
            e1 += __shfl_xor(e1, off);
        }
        float p0e = v0 ? exp2f(d0) : 0.0f;
        float p1e = v1 ? exp2f(d1) : 0.0f;
        float dist0 = sqrtf(e0), dist1 = sqrtf(e1);
        psum += p0e + p1e;

        v2f v0a = fp8x2<false>(vc0.x), v0b = fp8x2<true>(vc0.x);
        v2f v1a = fp8x2<false>(vc1.x), v1b = fp8x2<true>(vc1.x);
        accx.x += p0e * v0a.x + p1e * v1a.x;
        accx.y += p0e * v0a.y + p1e * v1a.y;
        accx.z += p0e * v0b.x + p1e * v1b.x;
        accx.w += p0e * v0b.y + p1e * v1b.y;
        accc.x += p0e * (dist0 * wc4.x + bc4.x) * dx0x
                + p1e * (dist1 * wc4.x + bc4.x) * dx1x;
        accc.y += p0e * (dist0 * wc4.y + bc4.y) * dx0y
                + p1e * (dist1 * wc4.y + bc4.y) * dx1y;
        accc.z += p0e * (dist0 * wc4.z + bc4.z) * dx0z
                + p1e * (dist1 * wc4.z + bc4.z) * dx1z;
        accc.w += p0e * (dist0 * wc4.w + bc4.w) * dx0w
                + p1e * (dist1 * wc4.w + bc4.w) * dx1w;
    }

    // cross-quarter combine (once per node)
    #pragma unroll
    for (int off = 16; off <= 32; off <<= 1) {
        accx.x += __shfl_xor(accx.x, off);
        accx.y += __shfl_xor(accx.y, off);
        accx.z += __shfl_xor(accx.z, off);
        accx.w += __shfl_xor(accx.w, off);
        accc.x += __shfl_xor(accc.x, off);
        accc.y += __shfl_xor(accc.y, off);
        accc.z += __shfl_xor(accc.z, off);
        accc.w += __shfl_xor(accc.w, off);
        psum   += __shfl_xor(psum, off);
    }
    if (lane < 16) {
        ((float4*)out_x)[(size_t)n * 16 + sl] = accx;   // unnormalized
        ((float4*)out_c)[(size_t)n * 16 + sl] = accc;
    }
    if (lane == 0) wsum[n] = psum;
}

// deterministic fixed-tree reduction of wsum -> S (single block)
__global__ __launch_bounds__(1024) void k_redsum(
    const float* __restrict__ wsum, float* __restrict__ S)
{
    __shared__ float red[16];
    float a = 0.0f;
    for (int i = threadIdx.x; i < N_NODES; i += 1024) a += wsum[i];
    #pragma unroll
    for (int off = 32; off; off >>= 1) a += __shfl_xor(a, off);
    if ((threadIdx.x & 63) == 0) red[threadIdx.x >> 6] = a;
    __syncthreads();
    if (threadIdx.x == 0) {
        float s = 0.0f;
        #pragma unroll
        for (int w = 0; w < 16; ++w) s += red[w];
        *S = s;
    }
}

// out = residual + out * (1/S), one float4 per thread
__global__ __launch_bounds__(256) void k_finalize(
    const float* __restrict__ x, const float* __restrict__ coord,
    const float* __restrict__ S, float* __restrict__ out)
{
    const float inv = 1.0f / *S;
    const int nd4 = (N_NODES * DIM) / 4;      // 800000
    const float4* x4 = (const float4*)x;
    const float4* c4 = (const float4*)coord;
    float4* o4 = (float4*)out;
    int i = blockIdx.x * 256 + threadIdx.x;
    if (i < 2 * nd4) {
        float4 r = (i < nd4) ? x4[i] : c4[i - nd4];
        float4 a = o4[i];
        a.x = r.x + a.x * inv;
        a.y = r.y + a.y * inv;
        a.z = r.z + a.z * inv;
        a.w = r.w + a.w * inv;
        o4[i] = a;
    }
}

extern "C" void kernel_launch(void* const* d_in, const int* in_sizes, int n_in,
                              void* d_out, int out_size, void* d_ws, size_t ws_size,
                              hipStream_t stream)
{
    const float* x     = (const float*)d_in[0];
    const float* coord = (const float*)d_in[1];
    const float* Wq    = (const float*)d_in[2];
    const float* bq    = (const float*)d_in[3];
    const float* Wk    = (const float*)d_in[4];
    const float* bk    = (const float*)d_in[5];
    const float* Wv    = (const float*)d_in[6];
    const float* bv    = (const float*)d_in[7];
    const float* Wc    = (const float*)d_in[8];
    const float* bc    = (const float*)d_in[9];
    const int*   eidx  = (const int*)d_in[10];

    float* out = (float*)d_out;
    float* ws  = (float*)d_ws;

    unsigned short* Qh  = (unsigned short*)ws;
    unsigned short* KVC = Qh + (size_t)N_NODES * 64;
    int* bucket_col = (int*)(KVC + (size_t)N_NODES * 128);   // 256B rows
    int* counts  = bucket_col + NE;
    int* offsets = counts + N_NODES;
    int* bsums   = offsets + N_NODES + 1;
    float* wsum  = (float*)(bsums + 256);
    float* S     = wsum + N_NODES;

    float* out_x = out;
    float* out_c = out + (size_t)N_NODES * DIM;

    // CSR build (row-bucketed column list), row-group-partitioned scatter
    (void)hipMemsetAsync(counts, 0, (size_t)N_NODES * sizeof(int), stream);
    k_hist  <<<NFILL_GRID, 256, 0, stream>>>(eidx, counts);
    k_scan1 <<<NSCAN_BLOCKS, 256, 0, stream>>>(counts, offsets, bsums);
    k_scan23<<<NSCAN_BLOCKS, 256, 0, stream>>>(offsets, counts, bsums);
    k_fill  <<<NFILL_GRID, 256, 0, stream>>>(eidx, counts, bucket_col);

    // node projections + packing (Q/K f16, V/C fp8 dword-interleaved)
    k_qkv<<<(N_NODES + 31) / 32, 256, 0, stream>>>(
        x, coord, Wq, bq, Wk, bk, Wv, bv, Qh, KVC);

    // fused edge pass (quarter-per-edge, 2x unrolled), acc -> d_out
    k_edge_fused<<<(N_NODES * 64 + 255) / 256, 256, 0, stream>>>(
        bucket_col, offsets, Qh, KVC, coord, Wc, bc, out_x, out_c, wsum);

    // deterministic global sum, then normalize + residual
    k_redsum<<<1, 1024, 0, stream>>>(wsum, S);
    k_finalize<<<(2 * N_NODES * DIM / 4 + 255) / 256, 256, 0, stream>>>(
        x, coord, S, out);
}